// Round 7
// baseline (426.899 us; speedup 1.0000x reference)
//
#include <hip/hip_runtime.h>

#define NN 100000
#define EE 1600000
#define CH 128
#define NG 512
#define OC 64

#define NB1 391          // ceil(NN/256) scan blocks

// workspace element offsets (4-byte units); total 68.9 MB
#define O_DINV   0
#define O_ROWS   100032   // 100001
#define O_DEG    200064   // 100000
#define O_BPART  300160   // 391
#define O_BOFFS  300672   // 391
#define O_START  301184   // 513
#define O_CSR    301888   // padded CSR, cap 2.50M words (sum pdeg <= 2.3M)
#define O_HS     2801920  // bf16 Hs: (NN+1) rows x 128 ushorts = 6400064 words
#define O_POS    9201984  // per-edge slot index: 1.6M words
#define O_WT1    10801984 // split W1: 32768 ushorts = 16384 words
#define O_WT2    10818368
#define O_A1     10834752 // bf16 A1: NN x 128 ushorts = 6.4M words

typedef __attribute__((ext_vector_type(8))) short short8v;
typedef __attribute__((ext_vector_type(4))) float float4v;

static __device__ __forceinline__ unsigned short f2bf(float x) {
  unsigned u = __float_as_uint(x);
  return (unsigned short)((u + 0x7FFFu + ((u >> 16) & 1u)) >> 16);  // RNE
}
static __device__ __forceinline__ float bf2f(unsigned short h) {
  return __uint_as_float((unsigned)h << 16);
}
static __device__ __forceinline__ unsigned pack2(float a, float b) {
  return (unsigned)f2bf(a) | ((unsigned)f2bf(b) << 16);
}
static __device__ __forceinline__ float bflo(unsigned v) {
  return __uint_as_float(v << 16);
}
static __device__ __forceinline__ float bfhi(unsigned v) {
  return __uint_as_float(v & 0xFFFF0000u);
}

// ---------------- prep: flat counting sort, full occupancy ----------------

__global__ void k_zero(int* __restrict__ deg) {
  int i = blockIdx.x * 256 + threadIdx.x;
  if (i < NN / 4) ((int4*)deg)[i] = make_int4(0, 0, 0, 0);
}

// pass 1: degree count + per-edge slot index (order within row is arbitrary;
// only reassociates fp32 adds in the aggregate, ~1e-7 effect)
__global__ void k_deg(const int* __restrict__ dst, int* __restrict__ deg,
                      int* __restrict__ pos) {
  int stride = gridDim.x * 256;
  for (int e = blockIdx.x * 256 + threadIdx.x; e < EE; e += stride)
    pos[e] = atomicAdd(&deg[dst[e]], 1);
}

// per-block 256-wide scan of PADDED degree; also dinv from real degree.
__global__ __launch_bounds__(256) void k_scan1(const int* __restrict__ deg,
                                               int* __restrict__ rows,
                                               int* __restrict__ bpart,
                                               float* __restrict__ dinv) {
  __shared__ int s[256];
  int b = blockIdx.x, t = threadIdx.x;
  int gid = b * 256 + t;
  int v = (gid < NN) ? deg[gid] : 0;
  if (gid < NN) dinv[gid] = rsqrtf((float)(v + 1));  // +1 self-loop
  int pdeg = (v + 7) & ~7;                           // pad to x8 for aggregate
  s[t] = pdeg;
  __syncthreads();
  for (int off = 1; off < 256; off <<= 1) {
    int u = (t >= off) ? s[t - off] : 0;
    __syncthreads();
    if (t >= off) s[t] += u;
    __syncthreads();
  }
  if (gid < NN) rows[gid] = s[t] - pdeg;   // block-local exclusive
  if (t == 255) bpart[b] = s[255];
}

__global__ void k_scan2(const int* __restrict__ bpart, int* __restrict__ boffs,
                        int* __restrict__ rows) {
  __shared__ int s[512];
  int t = threadIdx.x;
  int v = (t < NB1) ? bpart[t] : 0;
  s[t] = v;
  __syncthreads();
  for (int off = 1; off < 512; off <<= 1) {
    int u = (t >= off) ? s[t - off] : 0;
    __syncthreads();
    if (t >= off) s[t] += u;
    __syncthreads();
  }
  if (t < NB1) boffs[t] = s[t] - v;
  if (t == 511) rows[NN] = s[511];         // total padded edges
}

// globalize rows + fused batch-starts.
__global__ void k_scan3(int* __restrict__ rows, const int* __restrict__ boffs,
                        const int* __restrict__ batch, int* __restrict__ start) {
  int i = blockIdx.x * 256 + threadIdx.x;
  if (i >= NN) return;
  rows[i] += boffs[i >> 8];
  int b = batch[i];
  int prev = (i == 0) ? -1 : batch[i - 1];
  for (int g = prev + 1; g <= b; ++g) start[g] = i;
  if (i == NN - 1)
    for (int g = b + 1; g <= NG; ++g) start[g] = NN;
}

// pass 2: place srcs at precomputed slots; pad slots (disjoint) -> dummy NN.
__global__ void k_fillpad(const int* __restrict__ src, const int* __restrict__ dst,
                          const int* __restrict__ pos, const int* __restrict__ rows,
                          const int* __restrict__ deg, int* __restrict__ csr) {
  int stride = gridDim.x * 256;
  int id = blockIdx.x * 256 + threadIdx.x;
  for (int e = id; e < EE; e += stride)
    csr[rows[dst[e]] + pos[e]] = src[e];
  for (int i = id; i < NN; i += stride) {
    int d = deg[i];
    int base = rows[i] + d;
    int end = rows[i] + ((d + 7) & ~7);
    for (int k = base; k < end; ++k) csr[k] = NN;  // dummy zero row
  }
}

// split W1,W2 (fp32 [k][n]) into bf16 hi/lo, transposed to [n][k]; one launch.
__global__ void k_wsplit(const float* __restrict__ W1, const float* __restrict__ W2,
                         unsigned short* __restrict__ wt1,
                         unsigned short* __restrict__ wt2) {
  int id = blockIdx.x * 256 + threadIdx.x;   // 32768
  const float* W = (id < 16384) ? W1 : W2;
  unsigned short* wt = (id < 16384) ? wt1 : wt2;
  int i = id & 16383;
  int k = i >> 7, n = i & 127;
  float w = W[i];
  unsigned short h = f2bf(w);
  unsigned short l = f2bf(w - bf2f(h));
  wt[n * 128 + k] = h;
  wt[16384 + n * 128 + k] = l;
}

// Layer-1: Hs(bf16) = diag(dinv) * (X_fp32 @ W) via split-bf16 MFMA (3 terms).
__global__ __launch_bounds__(256) void k_gemm_mfma(
    const float* __restrict__ X, const unsigned short* __restrict__ wth,
    const unsigned short* __restrict__ wtl, const float* __restrict__ dinv,
    unsigned short* __restrict__ Hs) {
  __shared__ __align__(16) unsigned short sWh[64 * 136];  // [n][k] pad 136
  __shared__ __align__(16) unsigned short sWl[64 * 136];
  __shared__ __align__(16) unsigned short sXh[128 * 40];  // [row][k-chunk 32] pad 40
  __shared__ __align__(16) unsigned short sXl[128 * 40];

  const int t = threadIdx.x;
  const int w = t >> 6, lane = t & 63;
  const int quad = lane >> 4, lr = lane & 15;
  const int row0 = blockIdx.x * 128;
  const int col0 = blockIdx.y * 64;

  // zero the dummy row NN (read by k_aggregate pad slots)
  if (blockIdx.x == 0 && blockIdx.y == 0 && t < 64)
    *(unsigned*)&Hs[(size_t)NN * CH + t * 2] = 0u;

#pragma unroll
  for (int j = 0; j < 8; ++j) {
    int id = t + j * 256;
    int n = id >> 5, kk = (id & 31) * 4;
    *(ushort4*)&sWh[n * 136 + kk] = *(const ushort4*)&wth[(col0 + n) * 128 + kk];
    *(ushort4*)&sWl[n * 136 + kk] = *(const ushort4*)&wtl[(col0 + n) * 128 + kk];
  }

  float4v acc[2][4];
#pragma unroll
  for (int mi = 0; mi < 2; ++mi)
#pragma unroll
    for (int ni = 0; ni < 4; ++ni) acc[mi][ni] = (float4v){0.f, 0.f, 0.f, 0.f};

  for (int ks = 0; ks < 4; ++ks) {
    const int k0 = ks * 32;
    if (ks) __syncthreads();
#pragma unroll
    for (int i = 0; i < 4; ++i) {
      int row = i * 32 + (t >> 3);
      int seg = t & 7;
      int gr = row0 + row;
      float4 xv = {0.f, 0.f, 0.f, 0.f};
      if (gr < NN) xv = *(const float4*)&X[(size_t)gr * CH + k0 + seg * 4];
      ushort4 h, l;
      h.x = f2bf(xv.x); l.x = f2bf(xv.x - bf2f(h.x));
      h.y = f2bf(xv.y); l.y = f2bf(xv.y - bf2f(h.y));
      h.z = f2bf(xv.z); l.z = f2bf(xv.z - bf2f(h.z));
      h.w = f2bf(xv.w); l.w = f2bf(xv.w - bf2f(h.w));
      *(ushort4*)&sXh[row * 40 + seg * 4] = h;
      *(ushort4*)&sXl[row * 40 + seg * 4] = l;
    }
    __syncthreads();

    short8v ah[2], al[2];
#pragma unroll
    for (int mi = 0; mi < 2; ++mi) {
      int r = w * 32 + mi * 16 + lr;
      ah[mi] = *(const short8v*)&sXh[r * 40 + quad * 8];
      al[mi] = *(const short8v*)&sXl[r * 40 + quad * 8];
    }
#pragma unroll
    for (int ni = 0; ni < 4; ++ni) {
      int n = ni * 16 + lr;
      short8v bh = *(const short8v*)&sWh[n * 136 + k0 + quad * 8];
      short8v bl = *(const short8v*)&sWl[n * 136 + k0 + quad * 8];
#pragma unroll
      for (int mi = 0; mi < 2; ++mi) {
        acc[mi][ni] = __builtin_amdgcn_mfma_f32_16x16x32_bf16(ah[mi], bh, acc[mi][ni], 0, 0, 0);
        acc[mi][ni] = __builtin_amdgcn_mfma_f32_16x16x32_bf16(ah[mi], bl, acc[mi][ni], 0, 0, 0);
        acc[mi][ni] = __builtin_amdgcn_mfma_f32_16x16x32_bf16(al[mi], bh, acc[mi][ni], 0, 0, 0);
      }
    }
  }

#pragma unroll
  for (int mi = 0; mi < 2; ++mi) {
#pragma unroll
    for (int r = 0; r < 4; ++r) {
      int grow = row0 + w * 32 + mi * 16 + quad * 4 + r;
      if (grow < NN) {
        float d = dinv[grow];
#pragma unroll
        for (int ni = 0; ni < 4; ++ni)
          Hs[(size_t)grow * CH + col0 + ni * 16 + lr] = f2bf(d * acc[mi][ni][r]);
      }
    }
  }
}

// Layer-2: Hs(bf16) = diag(dinv) * (A_bf16 @ W). A is exact bf16 (lo=0):
// only 2 MFMA terms (AWh + AWl), no conversion in staging, half the reads.
__global__ __launch_bounds__(256) void k_gemm_bf(
    const unsigned short* __restrict__ A, const unsigned short* __restrict__ wth,
    const unsigned short* __restrict__ wtl, const float* __restrict__ dinv,
    unsigned short* __restrict__ Hs) {
  __shared__ __align__(16) unsigned short sWh[64 * 136];
  __shared__ __align__(16) unsigned short sWl[64 * 136];
  __shared__ __align__(16) unsigned short sA[128 * 40];

  const int t = threadIdx.x;
  const int w = t >> 6, lane = t & 63;
  const int quad = lane >> 4, lr = lane & 15;
  const int row0 = blockIdx.x * 128;
  const int col0 = blockIdx.y * 64;

  if (blockIdx.x == 0 && blockIdx.y == 0 && t < 64)
    *(unsigned*)&Hs[(size_t)NN * CH + t * 2] = 0u;

#pragma unroll
  for (int j = 0; j < 8; ++j) {
    int id = t + j * 256;
    int n = id >> 5, kk = (id & 31) * 4;
    *(ushort4*)&sWh[n * 136 + kk] = *(const ushort4*)&wth[(col0 + n) * 128 + kk];
    *(ushort4*)&sWl[n * 136 + kk] = *(const ushort4*)&wtl[(col0 + n) * 128 + kk];
  }

  float4v acc[2][4];
#pragma unroll
  for (int mi = 0; mi < 2; ++mi)
#pragma unroll
    for (int ni = 0; ni < 4; ++ni) acc[mi][ni] = (float4v){0.f, 0.f, 0.f, 0.f};

  for (int ks = 0; ks < 4; ++ks) {
    const int k0 = ks * 32;
    if (ks) __syncthreads();
    // stage A[row0..row0+127][k0..k0+31] bf16: 8 KB, each thread 2x ushort4
#pragma unroll
    for (int i = 0; i < 2; ++i) {
      int id = t + i * 256;          // 512 ushort4 segments
      int row = id >> 2, seg = id & 3;
      int gr = row0 + row;
      ushort4 v = {0, 0, 0, 0};
      if (gr < NN) v = *(const ushort4*)&A[(size_t)gr * CH + k0 + seg * 8];
      *(ushort4*)&sA[row * 40 + seg * 8] = v;
      ushort4 v2 = {0, 0, 0, 0};
      if (gr < NN) v2 = *(const ushort4*)&A[(size_t)gr * CH + k0 + seg * 8 + 4];
      *(ushort4*)&sA[row * 40 + seg * 8 + 4] = v2;
    }
    __syncthreads();

    short8v ah[2];
#pragma unroll
    for (int mi = 0; mi < 2; ++mi) {
      int r = w * 32 + mi * 16 + lr;
      ah[mi] = *(const short8v*)&sA[r * 40 + quad * 8];
    }
#pragma unroll
    for (int ni = 0; ni < 4; ++ni) {
      int n = ni * 16 + lr;
      short8v bh = *(const short8v*)&sWh[n * 136 + k0 + quad * 8];
      short8v bl = *(const short8v*)&sWl[n * 136 + k0 + quad * 8];
#pragma unroll
      for (int mi = 0; mi < 2; ++mi) {
        acc[mi][ni] = __builtin_amdgcn_mfma_f32_16x16x32_bf16(ah[mi], bh, acc[mi][ni], 0, 0, 0);
        acc[mi][ni] = __builtin_amdgcn_mfma_f32_16x16x32_bf16(ah[mi], bl, acc[mi][ni], 0, 0, 0);
      }
    }
  }

#pragma unroll
  for (int mi = 0; mi < 2; ++mi) {
#pragma unroll
    for (int r = 0; r < 4; ++r) {
      int grow = row0 + w * 32 + mi * 16 + quad * 4 + r;
      if (grow < NN) {
        float d = dinv[grow];
#pragma unroll
        for (int ni = 0; ni < 4; ++ni)
          Hs[(size_t)grow * CH + col0 + ni * 16 + lr] = f2bf(d * acc[mi][ni][r]);
      }
    }
  }
}

// out(bf16)[i] = relu(dinv[i]*(Hs[i] + sum Hs[csr[e]]) + b). One wave per node.
// dwordx2 gathers: lanes 0-31 take even edges, 32-63 odd edges of each 8-group;
// each lane owns 4 channels; one shfl_xor(32) combines halves. (verified 60 us)
__global__ __launch_bounds__(256) void k_aggregate(
    const uint2* __restrict__ H2, const int* __restrict__ rows,
    const int* __restrict__ csr, const float* __restrict__ dinv,
    const float* __restrict__ bias, uint2* __restrict__ out) {
  int node = blockIdx.x * 4 + (threadIdx.x >> 6);
  if (node >= NN) return;
  int lane = threadIdx.x & 63;
  int h = lane >> 5, li = lane & 31;
  float a0 = 0.f, a1 = 0.f, a2 = 0.f, a3 = 0.f;
  int e0 = rows[node], e1 = rows[node + 1];  // padded, multiple of 8
  int nr = (e1 - e0) >> 3;                   // rounds of 8 edges
  if (nr) {
    const int* cp = csr + e0 + h;            // half h reads edges e0+h, e0+h+2, ...
    uint2 va[4], vb[4];

#define LOADQ(buf)                                                          \
  do {                                                                      \
    unsigned s0_ = (unsigned)cp[0], s1_ = (unsigned)cp[2];                  \
    unsigned s2_ = (unsigned)cp[4], s3_ = (unsigned)cp[6];                  \
    buf[0] = H2[(s0_ << 5) | li];                                           \
    buf[1] = H2[(s1_ << 5) | li];                                           \
    buf[2] = H2[(s2_ << 5) | li];                                           \
    buf[3] = H2[(s3_ << 5) | li];                                           \
    cp += 8;                                                                \
  } while (0)

#define ACCQ(buf)                                                           \
  do {                                                                      \
    _Pragma("unroll")                                                       \
    for (int k_ = 0; k_ < 4; ++k_) {                                        \
      a0 += bflo(buf[k_].x); a1 += bfhi(buf[k_].x);                         \
      a2 += bflo(buf[k_].y); a3 += bfhi(buf[k_].y);                         \
    }                                                                       \
  } while (0)

    LOADQ(va);
    int rem = nr - 1;
    while (rem >= 2) {
      LOADQ(vb); ACCQ(va);
      LOADQ(va); ACCQ(vb);
      rem -= 2;
    }
    if (rem) { LOADQ(vb); ACCQ(va); ACCQ(vb); }
    else     { ACCQ(va); }
#undef LOADQ
#undef ACCQ
  }
  // combine even-edge (h=0) and odd-edge (h=1) partial sums
  a0 += __shfl_xor(a0, 32);
  a1 += __shfl_xor(a1, 32);
  a2 += __shfl_xor(a2, 32);
  a3 += __shfl_xor(a3, 32);
  // self-loop term
  uint2 sv = H2[((unsigned)node << 5) | li];
  a0 += bflo(sv.x); a1 += bfhi(sv.x);
  a2 += bflo(sv.y); a3 += bfhi(sv.y);
  float d = dinv[node];
  float4 b4 = *(const float4*)&bias[li << 2];
  float o0 = fmaxf(fmaf(d, a0, b4.x), 0.f);
  float o1 = fmaxf(fmaf(d, a1, b4.y), 0.f);
  float o2 = fmaxf(fmaf(d, a2, b4.z), 0.f);
  float o3 = fmaxf(fmaf(d, a3, b4.w), 0.f);
  if (!h)
    out[((unsigned)node << 5) | li] = make_uint2(pack2(o0, o1), pack2(o2, o3));
}

// Fused per-graph pipeline: segmented mean pool (bf16 A) -> MLP1 -> MLP2 -> out.
__global__ __launch_bounds__(256) void k_head(
    const unsigned short* __restrict__ A, const int* __restrict__ start,
    const float* __restrict__ W3, const float* __restrict__ b3,
    const float* __restrict__ W4, const float* __restrict__ b4,
    float* __restrict__ out) {
  __shared__ float pooled[128];
  __shared__ float part[128];
  __shared__ float g1[128];
  int g = blockIdx.x;
  int c = threadIdx.x & 127;
  int half = threadIdx.x >> 7;
  int s0 = start[g], s1 = start[g + 1];
  float sum = 0.f;
  for (int i = s0 + half; i < s1; i += 2)
    sum += bf2f(A[(size_t)i * CH + c]);
  if (half) part[c] = sum;
  __syncthreads();
  if (!half) {
    float n = fmaxf((float)(s1 - s0), 1.0f);
    pooled[c] = (sum + part[c]) / n;
  }
  __syncthreads();
  if (threadIdx.x < 128) {
    float acc = b3[c];
    for (int k = 0; k < 128; ++k) acc += pooled[k] * W3[k * CH + c];
    g1[c] = fmaxf(acc, 0.f);
  }
  __syncthreads();
  if (threadIdx.x < 64) {
    float acc = b4[threadIdx.x];
    for (int k = 0; k < 128; ++k) acc += g1[k] * W4[k * OC + threadIdx.x];
    out[(size_t)g * OC + threadIdx.x] = acc;
  }
}

extern "C" void kernel_launch(void* const* d_in, const int* in_sizes, int n_in,
                              void* d_out, int out_size, void* d_ws, size_t ws_size,
                              hipStream_t stream) {
  const float* X   = (const float*)d_in[0];
  const int* ei    = (const int*)d_in[1];
  const int* batch = (const int*)d_in[2];
  const float* W1  = (const float*)d_in[3];
  const float* b1  = (const float*)d_in[4];
  const float* W2  = (const float*)d_in[5];
  const float* b2  = (const float*)d_in[6];
  const float* W3  = (const float*)d_in[7];
  const float* b3  = (const float*)d_in[8];
  const float* W4  = (const float*)d_in[9];
  const float* b4  = (const float*)d_in[10];
  float* out = (float*)d_out;
  float* ws = (float*)d_ws;

  const int* src = ei;        // edge_index[0]
  const int* dst = ei + EE;   // edge_index[1]

  float* dinv = ws + O_DINV;
  int* rows   = (int*)(ws + O_ROWS);
  int* deg    = (int*)(ws + O_DEG);
  int* bpart  = (int*)(ws + O_BPART);
  int* boffs  = (int*)(ws + O_BOFFS);
  int* start  = (int*)(ws + O_START);
  int* csr    = (int*)(ws + O_CSR);
  unsigned short* Hs = (unsigned short*)(ws + O_HS);
  int* pos    = (int*)(ws + O_POS);
  unsigned short* wt1 = (unsigned short*)(ws + O_WT1);
  unsigned short* wt2 = (unsigned short*)(ws + O_WT2);
  unsigned short* A1 = (unsigned short*)(ws + O_A1);

  // prep: flat counting sort at full occupancy
  k_zero<<<98, 256, 0, stream>>>(deg);
  k_deg<<<2048, 256, 0, stream>>>(dst, deg, pos);
  k_scan1<<<NB1, 256, 0, stream>>>(deg, rows, bpart, dinv);
  k_scan2<<<1, 512, 0, stream>>>(bpart, boffs, rows);
  k_scan3<<<NB1, 256, 0, stream>>>(rows, boffs, batch, start);
  k_fillpad<<<2048, 256, 0, stream>>>(src, dst, pos, rows, deg, csr);
  k_wsplit<<<128, 256, 0, stream>>>(W1, W2, wt1, wt2);

  dim3 ggrid((NN + 127) / 128, 2);
  // layer 1 (fp32 X input, 3-term split MFMA)
  k_gemm_mfma<<<ggrid, 256, 0, stream>>>(X, wt1, wt1 + 16384, dinv, Hs);
  k_aggregate<<<(NN + 3) / 4, 256, 0, stream>>>((const uint2*)Hs, rows, csr, dinv, b1, (uint2*)A1);
  // layer 2 (bf16 A1 input, 2-term MFMA)
  k_gemm_bf<<<ggrid, 256, 0, stream>>>(A1, wt2, wt2 + 16384, dinv, Hs);
  k_aggregate<<<(NN + 3) / 4, 256, 0, stream>>>((const uint2*)Hs, rows, csr, dinv, b2, (uint2*)A1);

  k_head<<<NG, 256, 0, stream>>>(A1, start, W3, b3, W4, b4, out);
}

// Round 8
// 372.721 us; speedup vs baseline: 1.1454x; 1.1454x over previous
//
#include <hip/hip_runtime.h>

#define NN 100000
#define EE 1600000
#define CH 128
#define NG 512
#define OC 64

// coarse radix partition: 98 buckets of 1024 nodes; fixed-capacity staging cells
#define CSH 10
#define NCB 98
#define PBLK 256
#define PCHUNK 6250     // 256*6250 = 1.6M exactly
#define SCAP 128        // per (block,bucket) cell: mean 63.8 + 8 sigma

// workspace element offsets (4-byte units); total 110.4 MB
#define O_DINV   0
#define O_ROWS   100032   // 100001
#define O_CNT    200064   // 25088
#define O_PART   225152
#define O_OFFS   225280
#define O_START  225408   // 513
#define O_CSR    225984   // padded CSR, cap 2.50M words (sum pdeg <= 2.3M)
#define O_HS     2726016  // bf16 Hs: (NN+1) rows x 128 ushorts = 6400064 words
#define O_STG    9126080  // staging 3.21M words (dead after k_place)
#define O_WT1    9126080  // split W1: 32768 ushorts = 16384 words
#define O_WT2    9142464
#define O_A1     14800448 // bf16 A1: NN x 128 ushorts = 6.4M words

typedef __attribute__((ext_vector_type(8))) short short8v;
typedef __attribute__((ext_vector_type(4))) float float4v;

static __device__ __forceinline__ unsigned short f2bf(float x) {
  unsigned u = __float_as_uint(x);
  return (unsigned short)((u + 0x7FFFu + ((u >> 16) & 1u)) >> 16);  // RNE
}
static __device__ __forceinline__ float bf2f(unsigned short h) {
  return __uint_as_float((unsigned)h << 16);
}
static __device__ __forceinline__ unsigned pack2(float a, float b) {
  return (unsigned)f2bf(a) | ((unsigned)f2bf(b) << 16);
}
static __device__ __forceinline__ float bflo(unsigned v) {
  return __uint_as_float(v << 16);
}
static __device__ __forceinline__ float bfhi(unsigned v) {
  return __uint_as_float(v & 0xFFFF0000u);
}

// LDS radix scatter: hist -> scan -> ordered LDS buffer -> contiguous run copies.
__global__ __launch_bounds__(1024) void k_part(const int* __restrict__ src,
                                               const int* __restrict__ dst,
                                               int* __restrict__ cnt,
                                               unsigned* __restrict__ stg) {
  __shared__ int hist[NCB];   // counts, then exclusive bases
  __shared__ int lcur[NCB];
  __shared__ unsigned lout[PCHUNK];
  int t = threadIdx.x;
  int e0 = blockIdx.x * PCHUNK;
  if (t < NCB) { hist[t] = 0; lcur[t] = 0; }
  __syncthreads();
  for (int e = e0 + t; e < e0 + PCHUNK; e += 1024)
    atomicAdd(&hist[dst[e] >> CSH], 1);
  __syncthreads();
  if (t == 0) {
    int s = 0;
    for (int i = 0; i < NCB; ++i) { int v = hist[i]; hist[i] = s; s += v; }
  }
  __syncthreads();
  for (int e = e0 + t; e < e0 + PCHUNK; e += 1024) {
    int d = dst[e];
    int b = d >> CSH;
    int p = hist[b] + atomicAdd(&lcur[b], 1);
    lout[p] = (unsigned)src[e] | ((unsigned)(d & 1023) << 17);
  }
  __syncthreads();
  int w = t >> 6, lane = t & 63;
  unsigned* mystg = stg + (size_t)blockIdx.x * NCB * SCAP;
  for (int b = w; b < NCB; b += 16) {
    int beg = hist[b];
    int end = (b == NCB - 1) ? PCHUNK : hist[b + 1];
    int n = min(end - beg, SCAP);
    for (int i = lane; i < n; i += 64) mystg[b * SCAP + i] = lout[beg + i];
    if (lane == 0) cnt[blockIdx.x * NCB + b] = n;
  }
}

// Per bucket: degree histogram, dinv (real deg), exclusive scan of PADDED deg.
__global__ __launch_bounds__(1024) void k_count(const unsigned* __restrict__ stg,
                                                const int* __restrict__ cnt,
                                                int* __restrict__ rows,
                                                int* __restrict__ part,
                                                float* __restrict__ dinv) {
  __shared__ int ldeg[1024];
  __shared__ int s[1024];
  int b = blockIdx.x;
  int t = threadIdx.x;
  int w = t >> 6, lane = t & 63;
  int gid = (b << CSH) + t;
  ldeg[t] = 0;
  __syncthreads();
  for (int blk = w; blk < PBLK; blk += 16) {
    int c = cnt[blk * NCB + b];
    const unsigned* p = stg + ((size_t)blk * NCB + b) * SCAP;
    for (int e = lane; e < c; e += 64) atomicAdd(&ldeg[p[e] >> 17], 1);
  }
  __syncthreads();
  int v = ldeg[t];
  if (gid < NN) dinv[gid] = rsqrtf((float)(v + 1));  // +1 self-loop (real deg)
  int pdeg = (v + 7) & ~7;                           // pad to x8 for aggregate
  s[t] = pdeg;
  __syncthreads();
  for (int off = 1; off < 1024; off <<= 1) {
    int u = (t >= off) ? s[t - off] : 0;
    __syncthreads();
    if (t >= off) s[t] += u;
    __syncthreads();
  }
  if (gid < NN) rows[gid] = s[t] - pdeg;    // bucket-local exclusive (padded)
  if (t == 1023) part[b] = s[t];            // bucket padded total
}

__global__ void k_scan_part(const int* __restrict__ part, int* __restrict__ offs) {
  __shared__ int s[128];
  int t = threadIdx.x;
  int v = (t < NCB) ? part[t] : 0;
  s[t] = v;
  __syncthreads();
  for (int off = 1; off < 128; off <<= 1) {
    int u = (t >= off) ? s[t - off] : 0;
    __syncthreads();
    if (t >= off) s[t] += u;
    __syncthreads();
  }
  if (t < NCB) offs[t] = s[t] - v;
}

// globalize rows + fused batch-starts. rows[NN] = total padded edges.
__global__ void k_scan_add(int* __restrict__ rows, const int* __restrict__ offs,
                           const int* __restrict__ part,
                           const int* __restrict__ batch, int* __restrict__ start) {
  int i = blockIdx.x * 256 + threadIdx.x;
  if (i >= NN) return;
  rows[i] += offs[i >> 10];
  if (i == 0) rows[NN] = offs[NCB - 1] + part[NCB - 1];
  int b = batch[i];
  int prev = (i == 0) ? -1 : batch[i - 1];
  for (int g = prev + 1; g <= b; ++g) start[g] = i;
  if (i == NN - 1)
    for (int g = b + 1; g <= NG; ++g) start[g] = NN;
}

// Per bucket: place srcs via LDS cursors; fill pad slots with dummy node NN.
__global__ __launch_bounds__(1024) void k_place(const unsigned* __restrict__ stg,
                                                const int* __restrict__ cnt,
                                                const int* __restrict__ rows,
                                                int* __restrict__ csr) {
  __shared__ int lrow[1024];
  __shared__ int lcur[1024];
  int b = blockIdx.x;
  int t = threadIdx.x;
  int w = t >> 6, lane = t & 63;
  int gid = (b << CSH) + t;
  lrow[t] = (gid < NN) ? rows[gid] : 0;
  lcur[t] = 0;
  __syncthreads();
  for (int blk = w; blk < PBLK; blk += 16) {
    int c = cnt[blk * NCB + b];
    const unsigned* p = stg + ((size_t)blk * NCB + b) * SCAP;
    for (int e = lane; e < c; e += 64) {
      unsigned x = p[e];
      int ld = x >> 17;
      int q = atomicAdd(&lcur[ld], 1);
      csr[lrow[ld] + q] = (int)(x & 0x1FFFFu);
    }
  }
  __syncthreads();
  int d = lcur[t];
  int pd = (d + 7) & ~7;
  int base = lrow[t];
  for (int i = d; i < pd; ++i) csr[base + i] = NN;  // dummy zero row
}

// split W1,W2 (fp32 [k][n]) into bf16 hi/lo, transposed to [n][k]; one launch.
__global__ void k_wsplit(const float* __restrict__ W1, const float* __restrict__ W2,
                         unsigned short* __restrict__ wt1,
                         unsigned short* __restrict__ wt2) {
  int id = blockIdx.x * 256 + threadIdx.x;   // 32768
  const float* W = (id < 16384) ? W1 : W2;
  unsigned short* wt = (id < 16384) ? wt1 : wt2;
  int i = id & 16383;
  int k = i >> 7, n = i & 127;
  float w = W[i];
  unsigned short h = f2bf(w);
  unsigned short l = f2bf(w - bf2f(h));
  wt[n * 128 + k] = h;
  wt[16384 + n * 128 + k] = l;
}

// Layer-1: Hs(bf16) = diag(dinv) * (X_fp32 @ W), split-bf16 MFMA (3 terms).
// One block per 128 rows computes ALL 128 output cols (X read ONCE, was 2x);
// W fragments read directly from global (L2/L1-resident, shared by all blocks).
__global__ __launch_bounds__(256) void k_gemm_mfma(
    const float* __restrict__ X, const unsigned short* __restrict__ wth,
    const unsigned short* __restrict__ wtl, const float* __restrict__ dinv,
    unsigned short* __restrict__ Hs) {
  __shared__ __align__(16) unsigned short sXh[128 * 40];  // [row][k-chunk 32] pad 40
  __shared__ __align__(16) unsigned short sXl[128 * 40];

  const int t = threadIdx.x;
  const int w = t >> 6, lane = t & 63;
  const int quad = lane >> 4, lr = lane & 15;
  const int row0 = blockIdx.x * 128;

  // zero the dummy row NN (read by k_aggregate pad slots)
  if (blockIdx.x == 0 && t < 64)
    *(unsigned*)&Hs[(size_t)NN * CH + t * 2] = 0u;

  float4v acc[2][8];
#pragma unroll
  for (int mi = 0; mi < 2; ++mi)
#pragma unroll
    for (int ni = 0; ni < 8; ++ni) acc[mi][ni] = (float4v){0.f, 0.f, 0.f, 0.f};

  for (int ks = 0; ks < 4; ++ks) {
    const int k0 = ks * 32;
    if (ks) __syncthreads();
#pragma unroll
    for (int i = 0; i < 4; ++i) {
      int row = i * 32 + (t >> 3);
      int seg = t & 7;
      int gr = row0 + row;
      float4 xv = {0.f, 0.f, 0.f, 0.f};
      if (gr < NN) xv = *(const float4*)&X[(size_t)gr * CH + k0 + seg * 4];
      ushort4 h, l;
      h.x = f2bf(xv.x); l.x = f2bf(xv.x - bf2f(h.x));
      h.y = f2bf(xv.y); l.y = f2bf(xv.y - bf2f(h.y));
      h.z = f2bf(xv.z); l.z = f2bf(xv.z - bf2f(h.z));
      h.w = f2bf(xv.w); l.w = f2bf(xv.w - bf2f(h.w));
      *(ushort4*)&sXh[row * 40 + seg * 4] = h;
      *(ushort4*)&sXl[row * 40 + seg * 4] = l;
    }
    __syncthreads();

    short8v ah[2], al[2];
#pragma unroll
    for (int mi = 0; mi < 2; ++mi) {
      int r = w * 32 + mi * 16 + lr;
      ah[mi] = *(const short8v*)&sXh[r * 40 + quad * 8];
      al[mi] = *(const short8v*)&sXl[r * 40 + quad * 8];
    }
#pragma unroll
    for (int ni = 0; ni < 8; ++ni) {
      int n = ni * 16 + lr;
      short8v bh = *(const short8v*)&wth[n * 128 + k0 + quad * 8];
      short8v bl = *(const short8v*)&wtl[n * 128 + k0 + quad * 8];
#pragma unroll
      for (int mi = 0; mi < 2; ++mi) {
        acc[mi][ni] = __builtin_amdgcn_mfma_f32_16x16x32_bf16(ah[mi], bh, acc[mi][ni], 0, 0, 0);
        acc[mi][ni] = __builtin_amdgcn_mfma_f32_16x16x32_bf16(ah[mi], bl, acc[mi][ni], 0, 0, 0);
        acc[mi][ni] = __builtin_amdgcn_mfma_f32_16x16x32_bf16(al[mi], bh, acc[mi][ni], 0, 0, 0);
      }
    }
  }

#pragma unroll
  for (int mi = 0; mi < 2; ++mi) {
#pragma unroll
    for (int r = 0; r < 4; ++r) {
      int grow = row0 + w * 32 + mi * 16 + quad * 4 + r;
      if (grow < NN) {
        float d = dinv[grow];
#pragma unroll
        for (int ni = 0; ni < 8; ++ni)
          Hs[(size_t)grow * CH + ni * 16 + lr] = f2bf(d * acc[mi][ni][r]);
      }
    }
  }
}

// Layer-2: Hs(bf16) = diag(dinv) * (A_bf16 @ W). A exact bf16: 2 MFMA terms.
// Same single-pass structure: A read once, W direct from global.
__global__ __launch_bounds__(256) void k_gemm_bf(
    const unsigned short* __restrict__ A, const unsigned short* __restrict__ wth,
    const unsigned short* __restrict__ wtl, const float* __restrict__ dinv,
    unsigned short* __restrict__ Hs) {
  __shared__ __align__(16) unsigned short sA[128 * 40];

  const int t = threadIdx.x;
  const int w = t >> 6, lane = t & 63;
  const int quad = lane >> 4, lr = lane & 15;
  const int row0 = blockIdx.x * 128;

  if (blockIdx.x == 0 && t < 64)
    *(unsigned*)&Hs[(size_t)NN * CH + t * 2] = 0u;

  float4v acc[2][8];
#pragma unroll
  for (int mi = 0; mi < 2; ++mi)
#pragma unroll
    for (int ni = 0; ni < 8; ++ni) acc[mi][ni] = (float4v){0.f, 0.f, 0.f, 0.f};

  for (int ks = 0; ks < 4; ++ks) {
    const int k0 = ks * 32;
    if (ks) __syncthreads();
    // stage A[row0..row0+127][k0..k0+31] bf16: 8 KB, each thread 2x ushort4
#pragma unroll
    for (int i = 0; i < 2; ++i) {
      int id = t + i * 256;          // 512 ushort4 segments
      int row = id >> 2, seg = id & 3;
      int gr = row0 + row;
      ushort4 v = {0, 0, 0, 0};
      if (gr < NN) v = *(const ushort4*)&A[(size_t)gr * CH + k0 + seg * 8];
      *(ushort4*)&sA[row * 40 + seg * 8] = v;
      ushort4 v2 = {0, 0, 0, 0};
      if (gr < NN) v2 = *(const ushort4*)&A[(size_t)gr * CH + k0 + seg * 8 + 4];
      *(ushort4*)&sA[row * 40 + seg * 8 + 4] = v2;
    }
    __syncthreads();

    short8v ah[2];
#pragma unroll
    for (int mi = 0; mi < 2; ++mi) {
      int r = w * 32 + mi * 16 + lr;
      ah[mi] = *(const short8v*)&sA[r * 40 + quad * 8];
    }
#pragma unroll
    for (int ni = 0; ni < 8; ++ni) {
      int n = ni * 16 + lr;
      short8v bh = *(const short8v*)&wth[n * 128 + k0 + quad * 8];
      short8v bl = *(const short8v*)&wtl[n * 128 + k0 + quad * 8];
#pragma unroll
      for (int mi = 0; mi < 2; ++mi) {
        acc[mi][ni] = __builtin_amdgcn_mfma_f32_16x16x32_bf16(ah[mi], bh, acc[mi][ni], 0, 0, 0);
        acc[mi][ni] = __builtin_amdgcn_mfma_f32_16x16x32_bf16(ah[mi], bl, acc[mi][ni], 0, 0, 0);
      }
    }
  }

#pragma unroll
  for (int mi = 0; mi < 2; ++mi) {
#pragma unroll
    for (int r = 0; r < 4; ++r) {
      int grow = row0 + w * 32 + mi * 16 + quad * 4 + r;
      if (grow < NN) {
        float d = dinv[grow];
#pragma unroll
        for (int ni = 0; ni < 8; ++ni)
          Hs[(size_t)grow * CH + ni * 16 + lr] = f2bf(d * acc[mi][ni][r]);
      }
    }
  }
}

// out(bf16)[i] = relu(dinv[i]*(Hs[i] + sum Hs[csr[e]]) + b). One wave per node.
// dwordx2 gathers: lanes 0-31 take even edges, 32-63 odd edges of each 8-group;
// each lane owns 4 channels; one shfl_xor(32) combines halves. (verified 60 us)
__global__ __launch_bounds__(256) void k_aggregate(
    const uint2* __restrict__ H2, const int* __restrict__ rows,
    const int* __restrict__ csr, const float* __restrict__ dinv,
    const float* __restrict__ bias, uint2* __restrict__ out) {
  int node = blockIdx.x * 4 + (threadIdx.x >> 6);
  if (node >= NN) return;
  int lane = threadIdx.x & 63;
  int h = lane >> 5, li = lane & 31;
  float a0 = 0.f, a1 = 0.f, a2 = 0.f, a3 = 0.f;
  int e0 = rows[node], e1 = rows[node + 1];  // padded, multiple of 8
  int nr = (e1 - e0) >> 3;                   // rounds of 8 edges
  if (nr) {
    const int* cp = csr + e0 + h;            // half h reads edges e0+h, e0+h+2, ...
    uint2 va[4], vb[4];

#define LOADQ(buf)                                                          \
  do {                                                                      \
    unsigned s0_ = (unsigned)cp[0], s1_ = (unsigned)cp[2];                  \
    unsigned s2_ = (unsigned)cp[4], s3_ = (unsigned)cp[6];                  \
    buf[0] = H2[(s0_ << 5) | li];                                           \
    buf[1] = H2[(s1_ << 5) | li];                                           \
    buf[2] = H2[(s2_ << 5) | li];                                           \
    buf[3] = H2[(s3_ << 5) | li];                                           \
    cp += 8;                                                                \
  } while (0)

#define ACCQ(buf)                                                           \
  do {                                                                      \
    _Pragma("unroll")                                                       \
    for (int k_ = 0; k_ < 4; ++k_) {                                        \
      a0 += bflo(buf[k_].x); a1 += bfhi(buf[k_].x);                         \
      a2 += bflo(buf[k_].y); a3 += bfhi(buf[k_].y);                         \
    }                                                                       \
  } while (0)

    LOADQ(va);
    int rem = nr - 1;
    while (rem >= 2) {
      LOADQ(vb); ACCQ(va);
      LOADQ(va); ACCQ(vb);
      rem -= 2;
    }
    if (rem) { LOADQ(vb); ACCQ(va); ACCQ(vb); }
    else     { ACCQ(va); }
#undef LOADQ
#undef ACCQ
  }
  // combine even-edge (h=0) and odd-edge (h=1) partial sums
  a0 += __shfl_xor(a0, 32);
  a1 += __shfl_xor(a1, 32);
  a2 += __shfl_xor(a2, 32);
  a3 += __shfl_xor(a3, 32);
  // self-loop term
  uint2 sv = H2[((unsigned)node << 5) | li];
  a0 += bflo(sv.x); a1 += bfhi(sv.x);
  a2 += bflo(sv.y); a3 += bfhi(sv.y);
  float d = dinv[node];
  float4 b4 = *(const float4*)&bias[li << 2];
  float o0 = fmaxf(fmaf(d, a0, b4.x), 0.f);
  float o1 = fmaxf(fmaf(d, a1, b4.y), 0.f);
  float o2 = fmaxf(fmaf(d, a2, b4.z), 0.f);
  float o3 = fmaxf(fmaf(d, a3, b4.w), 0.f);
  if (!h)
    out[((unsigned)node << 5) | li] = make_uint2(pack2(o0, o1), pack2(o2, o3));
}

// Fused per-graph pipeline: segmented mean pool -> MLP1 -> MLP2 -> out.
// Pooling vectorized: short8 (16 B) loads, 16 rows x 16 channel-octets/block.
__global__ __launch_bounds__(256) void k_head(
    const unsigned short* __restrict__ A, const int* __restrict__ start,
    const float* __restrict__ W3, const float* __restrict__ b3,
    const float* __restrict__ W4, const float* __restrict__ b4,
    float* __restrict__ out) {
  __shared__ float ppart[16][128];
  __shared__ float pooled[128];
  __shared__ float g1[128];
  int g = blockIdx.x;
  int t = threadIdx.x;
  int c8 = t & 15;            // channel octet 0..15
  int r = t >> 4;             // row slot 0..15
  int s0 = start[g], s1 = start[g + 1];
  float s[8] = {0.f, 0.f, 0.f, 0.f, 0.f, 0.f, 0.f, 0.f};
  for (int i = s0 + r; i < s1; i += 16) {
    short8v v = *(const short8v*)&A[(size_t)i * CH + c8 * 8];
#pragma unroll
    for (int j = 0; j < 8; ++j) s[j] += bf2f((unsigned short)v[j]);
  }
#pragma unroll
  for (int j = 0; j < 8; ++j) ppart[r][c8 * 8 + j] = s[j];
  __syncthreads();
  if (t < 128) {
    float n = fmaxf((float)(s1 - s0), 1.0f);
    float acc = 0.f;
#pragma unroll
    for (int rr = 0; rr < 16; ++rr) acc += ppart[rr][t];
    pooled[t] = acc / n;
  }
  __syncthreads();
  if (t < 128) {
    float acc = b3[t];
    for (int k = 0; k < 128; ++k) acc += pooled[k] * W3[k * CH + t];
    g1[t] = fmaxf(acc, 0.f);
  }
  __syncthreads();
  if (t < 64) {
    float acc = b4[t];
    for (int k = 0; k < 128; ++k) acc += g1[k] * W4[k * OC + t];
    out[(size_t)g * OC + t] = acc;
  }
}

extern "C" void kernel_launch(void* const* d_in, const int* in_sizes, int n_in,
                              void* d_out, int out_size, void* d_ws, size_t ws_size,
                              hipStream_t stream) {
  const float* X   = (const float*)d_in[0];
  const int* ei    = (const int*)d_in[1];
  const int* batch = (const int*)d_in[2];
  const float* W1  = (const float*)d_in[3];
  const float* b1  = (const float*)d_in[4];
  const float* W2  = (const float*)d_in[5];
  const float* b2  = (const float*)d_in[6];
  const float* W3  = (const float*)d_in[7];
  const float* b3  = (const float*)d_in[8];
  const float* W4  = (const float*)d_in[9];
  const float* b4  = (const float*)d_in[10];
  float* out = (float*)d_out;
  float* ws = (float*)d_ws;

  const int* src = ei;        // edge_index[0]
  const int* dst = ei + EE;   // edge_index[1]

  float* dinv = ws + O_DINV;
  int* rows   = (int*)(ws + O_ROWS);
  int* cnt    = (int*)(ws + O_CNT);
  int* part   = (int*)(ws + O_PART);
  int* offs   = (int*)(ws + O_OFFS);
  int* start  = (int*)(ws + O_START);
  int* csr    = (int*)(ws + O_CSR);
  unsigned short* Hs = (unsigned short*)(ws + O_HS);
  unsigned* stg = (unsigned*)(ws + O_STG);
  unsigned short* wt1 = (unsigned short*)(ws + O_WT1);
  unsigned short* wt2 = (unsigned short*)(ws + O_WT2);
  unsigned short* A1 = (unsigned short*)(ws + O_A1);

  k_part<<<PBLK, 1024, 0, stream>>>(src, dst, cnt, stg);
  k_count<<<NCB, 1024, 0, stream>>>(stg, cnt, rows, part, dinv);
  k_scan_part<<<1, 128, 0, stream>>>(part, offs);
  k_scan_add<<<(NN + 255) / 256, 256, 0, stream>>>(rows, offs, part, batch, start);
  k_place<<<NCB, 1024, 0, stream>>>(stg, cnt, rows, csr);
  // after k_place the staging region is dead; wt1/wt2 overwrite its start
  k_wsplit<<<128, 256, 0, stream>>>(W1, W2, wt1, wt2);

  int ggrid = (NN + 127) / 128;
  // layer 1 (fp32 X input, 3-term split MFMA; X read once, W from L2)
  k_gemm_mfma<<<ggrid, 256, 0, stream>>>(X, wt1, wt1 + 16384, dinv, Hs);
  k_aggregate<<<(NN + 3) / 4, 256, 0, stream>>>((const uint2*)Hs, rows, csr, dinv, b1, (uint2*)A1);
  // layer 2 (bf16 A1 input, 2-term MFMA)
  k_gemm_bf<<<ggrid, 256, 0, stream>>>(A1, wt2, wt2 + 16384, dinv, Hs);
  k_aggregate<<<(NN + 3) / 4, 256, 0, stream>>>((const uint2*)Hs, rows, csr, dinv, b2, (uint2*)A1);

  k_head<<<NG, 256, 0, stream>>>(A1, start, W3, b3, W4, b4, out);
}

// Round 9
// 352.014 us; speedup vs baseline: 1.2127x; 1.0588x over previous
//
#include <hip/hip_runtime.h>

#define NN 100000
#define EE 1600000
#define CH 128
#define NG 512
#define OC 64

// coarse radix partition: 98 buckets of 1024 nodes; fixed-capacity staging cells
#define CSH 10
#define NCB 98
#define PBLK 256
#define PCHUNK 6250     // 256*6250 = 1.6M exactly
#define SCAP 128        // per (block,bucket) cell: mean 63.8 + 8 sigma

// workspace element offsets (4-byte units); total 110.4 MB
#define O_DINV   0
#define O_ROWS   100032   // 100001
#define O_CNT    200064   // 25088
#define O_PART   225152
#define O_OFFS   225280
#define O_START  225408   // 513
#define O_CSR    225984   // padded CSR, cap 2.50M words (sum pdeg <= 2.3M)
#define O_HS     2726016  // bf16 Hs: (NN+1) rows x 128 ushorts = 6400064 words
#define O_STG    9126080  // staging 3.21M words (dead after k_place)
#define O_WT1    9126080  // split W1: 32768 ushorts = 16384 words
#define O_WT2    9142464
#define O_A1     14800448 // bf16 A1: NN x 128 ushorts = 6.4M words

typedef __attribute__((ext_vector_type(8))) short short8v;
typedef __attribute__((ext_vector_type(4))) float float4v;

static __device__ __forceinline__ unsigned short f2bf(float x) {
  unsigned u = __float_as_uint(x);
  return (unsigned short)((u + 0x7FFFu + ((u >> 16) & 1u)) >> 16);  // RNE
}
static __device__ __forceinline__ float bf2f(unsigned short h) {
  return __uint_as_float((unsigned)h << 16);
}
static __device__ __forceinline__ unsigned pack2(float a, float b) {
  return (unsigned)f2bf(a) | ((unsigned)f2bf(b) << 16);
}
static __device__ __forceinline__ float bflo(unsigned v) {
  return __uint_as_float(v << 16);
}
static __device__ __forceinline__ float bfhi(unsigned v) {
  return __uint_as_float(v & 0xFFFF0000u);
}

// LDS radix scatter: hist -> scan -> ordered LDS buffer -> contiguous run copies.
__global__ __launch_bounds__(1024) void k_part(const int* __restrict__ src,
                                               const int* __restrict__ dst,
                                               int* __restrict__ cnt,
                                               unsigned* __restrict__ stg) {
  __shared__ int hist[NCB];   // counts, then exclusive bases
  __shared__ int lcur[NCB];
  __shared__ unsigned lout[PCHUNK];
  int t = threadIdx.x;
  int e0 = blockIdx.x * PCHUNK;
  if (t < NCB) { hist[t] = 0; lcur[t] = 0; }
  __syncthreads();
  for (int e = e0 + t; e < e0 + PCHUNK; e += 1024)
    atomicAdd(&hist[dst[e] >> CSH], 1);
  __syncthreads();
  if (t == 0) {
    int s = 0;
    for (int i = 0; i < NCB; ++i) { int v = hist[i]; hist[i] = s; s += v; }
  }
  __syncthreads();
  for (int e = e0 + t; e < e0 + PCHUNK; e += 1024) {
    int d = dst[e];
    int b = d >> CSH;
    int p = hist[b] + atomicAdd(&lcur[b], 1);
    lout[p] = (unsigned)src[e] | ((unsigned)(d & 1023) << 17);
  }
  __syncthreads();
  int w = t >> 6, lane = t & 63;
  unsigned* mystg = stg + (size_t)blockIdx.x * NCB * SCAP;
  for (int b = w; b < NCB; b += 16) {
    int beg = hist[b];
    int end = (b == NCB - 1) ? PCHUNK : hist[b + 1];
    int n = min(end - beg, SCAP);
    for (int i = lane; i < n; i += 64) mystg[b * SCAP + i] = lout[beg + i];
    if (lane == 0) cnt[blockIdx.x * NCB + b] = n;
  }
}

// Per bucket: degree histogram, dinv (real deg), exclusive scan of PADDED deg.
__global__ __launch_bounds__(1024) void k_count(const unsigned* __restrict__ stg,
                                                const int* __restrict__ cnt,
                                                int* __restrict__ rows,
                                                int* __restrict__ part,
                                                float* __restrict__ dinv) {
  __shared__ int ldeg[1024];
  __shared__ int s[1024];
  int b = blockIdx.x;
  int t = threadIdx.x;
  int w = t >> 6, lane = t & 63;
  int gid = (b << CSH) + t;
  ldeg[t] = 0;
  __syncthreads();
  for (int blk = w; blk < PBLK; blk += 16) {
    int c = cnt[blk * NCB + b];
    const unsigned* p = stg + ((size_t)blk * NCB + b) * SCAP;
    for (int e = lane; e < c; e += 64) atomicAdd(&ldeg[p[e] >> 17], 1);
  }
  __syncthreads();
  int v = ldeg[t];
  if (gid < NN) dinv[gid] = rsqrtf((float)(v + 1));  // +1 self-loop (real deg)
  int pdeg = (v + 7) & ~7;                           // pad to x8 for aggregate
  s[t] = pdeg;
  __syncthreads();
  for (int off = 1; off < 1024; off <<= 1) {
    int u = (t >= off) ? s[t - off] : 0;
    __syncthreads();
    if (t >= off) s[t] += u;
    __syncthreads();
  }
  if (gid < NN) rows[gid] = s[t] - pdeg;    // bucket-local exclusive (padded)
  if (t == 1023) part[b] = s[t];            // bucket padded total
}

__global__ void k_scan_part(const int* __restrict__ part, int* __restrict__ offs) {
  __shared__ int s[128];
  int t = threadIdx.x;
  int v = (t < NCB) ? part[t] : 0;
  s[t] = v;
  __syncthreads();
  for (int off = 1; off < 128; off <<= 1) {
    int u = (t >= off) ? s[t - off] : 0;
    __syncthreads();
    if (t >= off) s[t] += u;
    __syncthreads();
  }
  if (t < NCB) offs[t] = s[t] - v;
}

// globalize rows + fused batch-starts. rows[NN] = total padded edges.
__global__ void k_scan_add(int* __restrict__ rows, const int* __restrict__ offs,
                           const int* __restrict__ part,
                           const int* __restrict__ batch, int* __restrict__ start) {
  int i = blockIdx.x * 256 + threadIdx.x;
  if (i >= NN) return;
  rows[i] += offs[i >> 10];
  if (i == 0) rows[NN] = offs[NCB - 1] + part[NCB - 1];
  int b = batch[i];
  int prev = (i == 0) ? -1 : batch[i - 1];
  for (int g = prev + 1; g <= b; ++g) start[g] = i;
  if (i == NN - 1)
    for (int g = b + 1; g <= NG; ++g) start[g] = NN;
}

// Per bucket: place srcs via LDS cursors; fill pad slots with dummy node NN.
__global__ __launch_bounds__(1024) void k_place(const unsigned* __restrict__ stg,
                                                const int* __restrict__ cnt,
                                                const int* __restrict__ rows,
                                                int* __restrict__ csr) {
  __shared__ int lrow[1024];
  __shared__ int lcur[1024];
  int b = blockIdx.x;
  int t = threadIdx.x;
  int w = t >> 6, lane = t & 63;
  int gid = (b << CSH) + t;
  lrow[t] = (gid < NN) ? rows[gid] : 0;
  lcur[t] = 0;
  __syncthreads();
  for (int blk = w; blk < PBLK; blk += 16) {
    int c = cnt[blk * NCB + b];
    const unsigned* p = stg + ((size_t)blk * NCB + b) * SCAP;
    for (int e = lane; e < c; e += 64) {
      unsigned x = p[e];
      int ld = x >> 17;
      int q = atomicAdd(&lcur[ld], 1);
      csr[lrow[ld] + q] = (int)(x & 0x1FFFFu);
    }
  }
  __syncthreads();
  int d = lcur[t];
  int pd = (d + 7) & ~7;
  int base = lrow[t];
  for (int i = d; i < pd; ++i) csr[base + i] = NN;  // dummy zero row
}

// split W1,W2 (fp32 [k][n]) into bf16 hi/lo, transposed to [n][k]; one launch.
__global__ void k_wsplit(const float* __restrict__ W1, const float* __restrict__ W2,
                         unsigned short* __restrict__ wt1,
                         unsigned short* __restrict__ wt2) {
  int id = blockIdx.x * 256 + threadIdx.x;   // 32768
  const float* W = (id < 16384) ? W1 : W2;
  unsigned short* wt = (id < 16384) ? wt1 : wt2;
  int i = id & 16383;
  int k = i >> 7, n = i & 127;
  float w = W[i];
  unsigned short h = f2bf(w);
  unsigned short l = f2bf(w - bf2f(h));
  wt[n * 128 + k] = h;
  wt[16384 + n * 128 + k] = l;
}

// Layer-1: Hs(bf16) = diag(dinv) * (X_fp32 @ W) via split-bf16 MFMA (3 terms).
// (782,2) grid, W staged in LDS — verified structure, GEMM stays < 60 us.
__global__ __launch_bounds__(256) void k_gemm_mfma(
    const float* __restrict__ X, const unsigned short* __restrict__ wth,
    const unsigned short* __restrict__ wtl, const float* __restrict__ dinv,
    unsigned short* __restrict__ Hs) {
  __shared__ __align__(16) unsigned short sWh[64 * 136];  // [n][k] pad 136
  __shared__ __align__(16) unsigned short sWl[64 * 136];
  __shared__ __align__(16) unsigned short sXh[128 * 40];  // [row][k-chunk 32] pad 40
  __shared__ __align__(16) unsigned short sXl[128 * 40];

  const int t = threadIdx.x;
  const int w = t >> 6, lane = t & 63;
  const int quad = lane >> 4, lr = lane & 15;
  const int row0 = blockIdx.x * 128;
  const int col0 = blockIdx.y * 64;

  // zero the dummy row NN (read by k_aggregate pad slots)
  if (blockIdx.x == 0 && blockIdx.y == 0 && t < 64)
    *(unsigned*)&Hs[(size_t)NN * CH + t * 2] = 0u;

#pragma unroll
  for (int j = 0; j < 8; ++j) {
    int id = t + j * 256;
    int n = id >> 5, kk = (id & 31) * 4;
    *(ushort4*)&sWh[n * 136 + kk] = *(const ushort4*)&wth[(col0 + n) * 128 + kk];
    *(ushort4*)&sWl[n * 136 + kk] = *(const ushort4*)&wtl[(col0 + n) * 128 + kk];
  }

  float4v acc[2][4];
#pragma unroll
  for (int mi = 0; mi < 2; ++mi)
#pragma unroll
    for (int ni = 0; ni < 4; ++ni) acc[mi][ni] = (float4v){0.f, 0.f, 0.f, 0.f};

  for (int ks = 0; ks < 4; ++ks) {
    const int k0 = ks * 32;
    if (ks) __syncthreads();
#pragma unroll
    for (int i = 0; i < 4; ++i) {
      int row = i * 32 + (t >> 3);
      int seg = t & 7;
      int gr = row0 + row;
      float4 xv = {0.f, 0.f, 0.f, 0.f};
      if (gr < NN) xv = *(const float4*)&X[(size_t)gr * CH + k0 + seg * 4];
      ushort4 h, l;
      h.x = f2bf(xv.x); l.x = f2bf(xv.x - bf2f(h.x));
      h.y = f2bf(xv.y); l.y = f2bf(xv.y - bf2f(h.y));
      h.z = f2bf(xv.z); l.z = f2bf(xv.z - bf2f(h.z));
      h.w = f2bf(xv.w); l.w = f2bf(xv.w - bf2f(h.w));
      *(ushort4*)&sXh[row * 40 + seg * 4] = h;
      *(ushort4*)&sXl[row * 40 + seg * 4] = l;
    }
    __syncthreads();

    short8v ah[2], al[2];
#pragma unroll
    for (int mi = 0; mi < 2; ++mi) {
      int r = w * 32 + mi * 16 + lr;
      ah[mi] = *(const short8v*)&sXh[r * 40 + quad * 8];
      al[mi] = *(const short8v*)&sXl[r * 40 + quad * 8];
    }
#pragma unroll
    for (int ni = 0; ni < 4; ++ni) {
      int n = ni * 16 + lr;
      short8v bh = *(const short8v*)&sWh[n * 136 + k0 + quad * 8];
      short8v bl = *(const short8v*)&sWl[n * 136 + k0 + quad * 8];
#pragma unroll
      for (int mi = 0; mi < 2; ++mi) {
        acc[mi][ni] = __builtin_amdgcn_mfma_f32_16x16x32_bf16(ah[mi], bh, acc[mi][ni], 0, 0, 0);
        acc[mi][ni] = __builtin_amdgcn_mfma_f32_16x16x32_bf16(ah[mi], bl, acc[mi][ni], 0, 0, 0);
        acc[mi][ni] = __builtin_amdgcn_mfma_f32_16x16x32_bf16(al[mi], bh, acc[mi][ni], 0, 0, 0);
      }
    }
  }

#pragma unroll
  for (int mi = 0; mi < 2; ++mi) {
#pragma unroll
    for (int r = 0; r < 4; ++r) {
      int grow = row0 + w * 32 + mi * 16 + quad * 4 + r;
      if (grow < NN) {
        float d = dinv[grow];
#pragma unroll
        for (int ni = 0; ni < 4; ++ni)
          Hs[(size_t)grow * CH + col0 + ni * 16 + lr] = f2bf(d * acc[mi][ni][r]);
      }
    }
  }
}

// Layer-2: Hs(bf16) = diag(dinv) * (A_bf16 @ W). A is exact bf16 (lo=0):
// only 2 MFMA terms (AWh + AWl), no conversion in staging, half the reads.
__global__ __launch_bounds__(256) void k_gemm_bf(
    const unsigned short* __restrict__ A, const unsigned short* __restrict__ wth,
    const unsigned short* __restrict__ wtl, const float* __restrict__ dinv,
    unsigned short* __restrict__ Hs) {
  __shared__ __align__(16) unsigned short sWh[64 * 136];
  __shared__ __align__(16) unsigned short sWl[64 * 136];
  __shared__ __align__(16) unsigned short sA[128 * 40];

  const int t = threadIdx.x;
  const int w = t >> 6, lane = t & 63;
  const int quad = lane >> 4, lr = lane & 15;
  const int row0 = blockIdx.x * 128;
  const int col0 = blockIdx.y * 64;

  if (blockIdx.x == 0 && blockIdx.y == 0 && t < 64)
    *(unsigned*)&Hs[(size_t)NN * CH + t * 2] = 0u;

#pragma unroll
  for (int j = 0; j < 8; ++j) {
    int id = t + j * 256;
    int n = id >> 5, kk = (id & 31) * 4;
    *(ushort4*)&sWh[n * 136 + kk] = *(const ushort4*)&wth[(col0 + n) * 128 + kk];
    *(ushort4*)&sWl[n * 136 + kk] = *(const ushort4*)&wtl[(col0 + n) * 128 + kk];
  }

  float4v acc[2][4];
#pragma unroll
  for (int mi = 0; mi < 2; ++mi)
#pragma unroll
    for (int ni = 0; ni < 4; ++ni) acc[mi][ni] = (float4v){0.f, 0.f, 0.f, 0.f};

  for (int ks = 0; ks < 4; ++ks) {
    const int k0 = ks * 32;
    if (ks) __syncthreads();
    // stage A[row0..row0+127][k0..k0+31] bf16: 8 KB, each thread 2x ushort4
#pragma unroll
    for (int i = 0; i < 2; ++i) {
      int id = t + i * 256;          // 512 ushort4 segments
      int row = id >> 2, seg = id & 3;
      int gr = row0 + row;
      ushort4 v = {0, 0, 0, 0};
      if (gr < NN) v = *(const ushort4*)&A[(size_t)gr * CH + k0 + seg * 8];
      *(ushort4*)&sA[row * 40 + seg * 8] = v;
      ushort4 v2 = {0, 0, 0, 0};
      if (gr < NN) v2 = *(const ushort4*)&A[(size_t)gr * CH + k0 + seg * 8 + 4];
      *(ushort4*)&sA[row * 40 + seg * 8 + 4] = v2;
    }
    __syncthreads();

    short8v ah[2];
#pragma unroll
    for (int mi = 0; mi < 2; ++mi) {
      int r = w * 32 + mi * 16 + lr;
      ah[mi] = *(const short8v*)&sA[r * 40 + quad * 8];
    }
#pragma unroll
    for (int ni = 0; ni < 4; ++ni) {
      int n = ni * 16 + lr;
      short8v bh = *(const short8v*)&sWh[n * 136 + k0 + quad * 8];
      short8v bl = *(const short8v*)&sWl[n * 136 + k0 + quad * 8];
#pragma unroll
      for (int mi = 0; mi < 2; ++mi) {
        acc[mi][ni] = __builtin_amdgcn_mfma_f32_16x16x32_bf16(ah[mi], bh, acc[mi][ni], 0, 0, 0);
        acc[mi][ni] = __builtin_amdgcn_mfma_f32_16x16x32_bf16(ah[mi], bl, acc[mi][ni], 0, 0, 0);
      }
    }
  }

#pragma unroll
  for (int mi = 0; mi < 2; ++mi) {
#pragma unroll
    for (int r = 0; r < 4; ++r) {
      int grow = row0 + w * 32 + mi * 16 + quad * 4 + r;
      if (grow < NN) {
        float d = dinv[grow];
#pragma unroll
        for (int ni = 0; ni < 4; ++ni)
          Hs[(size_t)grow * CH + col0 + ni * 16 + lr] = f2bf(d * acc[mi][ni][r]);
      }
    }
  }
}

// out(bf16)[i] = relu(dinv[i]*(Hs[i] + sum Hs[csr[e]]) + b). One wave per node.
// dwordx2 gathers: lanes 0-31 take even edges, 32-63 odd edges of each 8-group;
// each lane owns 4 channels; one shfl_xor(32) combines halves. (verified 60 us)
__global__ __launch_bounds__(256) void k_aggregate(
    const uint2* __restrict__ H2, const int* __restrict__ rows,
    const int* __restrict__ csr, const float* __restrict__ dinv,
    const float* __restrict__ bias, uint2* __restrict__ out) {
  int node = blockIdx.x * 4 + (threadIdx.x >> 6);
  if (node >= NN) return;
  int lane = threadIdx.x & 63;
  int h = lane >> 5, li = lane & 31;
  float a0 = 0.f, a1 = 0.f, a2 = 0.f, a3 = 0.f;
  int e0 = rows[node], e1 = rows[node + 1];  // padded, multiple of 8
  int nr = (e1 - e0) >> 3;                   // rounds of 8 edges
  if (nr) {
    const int* cp = csr + e0 + h;            // half h reads edges e0+h, e0+h+2, ...
    uint2 va[4], vb[4];

#define LOADQ(buf)                                                          \
  do {                                                                      \
    unsigned s0_ = (unsigned)cp[0], s1_ = (unsigned)cp[2];                  \
    unsigned s2_ = (unsigned)cp[4], s3_ = (unsigned)cp[6];                  \
    buf[0] = H2[(s0_ << 5) | li];                                           \
    buf[1] = H2[(s1_ << 5) | li];                                           \
    buf[2] = H2[(s2_ << 5) | li];                                           \
    buf[3] = H2[(s3_ << 5) | li];                                           \
    cp += 8;                                                                \
  } while (0)

#define ACCQ(buf)                                                           \
  do {                                                                      \
    _Pragma("unroll")                                                       \
    for (int k_ = 0; k_ < 4; ++k_) {                                        \
      a0 += bflo(buf[k_].x); a1 += bfhi(buf[k_].x);                         \
      a2 += bflo(buf[k_].y); a3 += bfhi(buf[k_].y);                         \
    }                                                                       \
  } while (0)

    LOADQ(va);
    int rem = nr - 1;
    while (rem >= 2) {
      LOADQ(vb); ACCQ(va);
      LOADQ(va); ACCQ(vb);
      rem -= 2;
    }
    if (rem) { LOADQ(vb); ACCQ(va); ACCQ(vb); }
    else     { ACCQ(va); }
#undef LOADQ
#undef ACCQ
  }
  // combine even-edge (h=0) and odd-edge (h=1) partial sums
  a0 += __shfl_xor(a0, 32);
  a1 += __shfl_xor(a1, 32);
  a2 += __shfl_xor(a2, 32);
  a3 += __shfl_xor(a3, 32);
  // self-loop term
  uint2 sv = H2[((unsigned)node << 5) | li];
  a0 += bflo(sv.x); a1 += bfhi(sv.x);
  a2 += bflo(sv.y); a3 += bfhi(sv.y);
  float d = dinv[node];
  float4 b4 = *(const float4*)&bias[li << 2];
  float o0 = fmaxf(fmaf(d, a0, b4.x), 0.f);
  float o1 = fmaxf(fmaf(d, a1, b4.y), 0.f);
  float o2 = fmaxf(fmaf(d, a2, b4.z), 0.f);
  float o3 = fmaxf(fmaf(d, a3, b4.w), 0.f);
  if (!h)
    out[((unsigned)node << 5) | li] = make_uint2(pack2(o0, o1), pack2(o2, o3));
}

// Fused per-graph pipeline: segmented mean pool -> MLP1 -> MLP2 -> out.
// Pooling vectorized: short8 (16 B) loads, 16 rows x 16 channel-octets/block.
__global__ __launch_bounds__(256) void k_head(
    const unsigned short* __restrict__ A, const int* __restrict__ start,
    const float* __restrict__ W3, const float* __restrict__ b3,
    const float* __restrict__ W4, const float* __restrict__ b4,
    float* __restrict__ out) {
  __shared__ float ppart[16][128];
  __shared__ float pooled[128];
  __shared__ float g1[128];
  int g = blockIdx.x;
  int t = threadIdx.x;
  int c8 = t & 15;            // channel octet 0..15
  int r = t >> 4;             // row slot 0..15
  int s0 = start[g], s1 = start[g + 1];
  float s[8] = {0.f, 0.f, 0.f, 0.f, 0.f, 0.f, 0.f, 0.f};
  for (int i = s0 + r; i < s1; i += 16) {
    short8v v = *(const short8v*)&A[(size_t)i * CH + c8 * 8];
#pragma unroll
    for (int j = 0; j < 8; ++j) s[j] += bf2f((unsigned short)v[j]);
  }
#pragma unroll
  for (int j = 0; j < 8; ++j) ppart[r][c8 * 8 + j] = s[j];
  __syncthreads();
  if (t < 128) {
    float n = fmaxf((float)(s1 - s0), 1.0f);
    float acc = 0.f;
#pragma unroll
    for (int rr = 0; rr < 16; ++rr) acc += ppart[rr][t];
    pooled[t] = acc / n;
  }
  __syncthreads();
  if (t < 128) {
    float acc = b3[t];
    for (int k = 0; k < 128; ++k) acc += pooled[k] * W3[k * CH + t];
    g1[t] = fmaxf(acc, 0.f);
  }
  __syncthreads();
  if (t < 64) {
    float acc = b4[t];
    for (int k = 0; k < 128; ++k) acc += g1[k] * W4[k * OC + t];
    out[(size_t)g * OC + t] = acc;
  }
}

extern "C" void kernel_launch(void* const* d_in, const int* in_sizes, int n_in,
                              void* d_out, int out_size, void* d_ws, size_t ws_size,
                              hipStream_t stream) {
  const float* X   = (const float*)d_in[0];
  const int* ei    = (const int*)d_in[1];
  const int* batch = (const int*)d_in[2];
  const float* W1  = (const float*)d_in[3];
  const float* b1  = (const float*)d_in[4];
  const float* W2  = (const float*)d_in[5];
  const float* b2  = (const float*)d_in[6];
  const float* W3  = (const float*)d_in[7];
  const float* b3  = (const float*)d_in[8];
  const float* W4  = (const float*)d_in[9];
  const float* b4  = (const float*)d_in[10];
  float* out = (float*)d_out;
  float* ws = (float*)d_ws;

  const int* src = ei;        // edge_index[0]
  const int* dst = ei + EE;   // edge_index[1]

  float* dinv = ws + O_DINV;
  int* rows   = (int*)(ws + O_ROWS);
  int* cnt    = (int*)(ws + O_CNT);
  int* part   = (int*)(ws + O_PART);
  int* offs   = (int*)(ws + O_OFFS);
  int* start  = (int*)(ws + O_START);
  int* csr    = (int*)(ws + O_CSR);
  unsigned short* Hs = (unsigned short*)(ws + O_HS);
  unsigned* stg = (unsigned*)(ws + O_STG);
  unsigned short* wt1 = (unsigned short*)(ws + O_WT1);
  unsigned short* wt2 = (unsigned short*)(ws + O_WT2);
  unsigned short* A1 = (unsigned short*)(ws + O_A1);

  k_part<<<PBLK, 1024, 0, stream>>>(src, dst, cnt, stg);
  k_count<<<NCB, 1024, 0, stream>>>(stg, cnt, rows, part, dinv);
  k_scan_part<<<1, 128, 0, stream>>>(part, offs);
  k_scan_add<<<(NN + 255) / 256, 256, 0, stream>>>(rows, offs, part, batch, start);
  k_place<<<NCB, 1024, 0, stream>>>(stg, cnt, rows, csr);
  // after k_place the staging region is dead; wt1/wt2 overwrite its start
  k_wsplit<<<128, 256, 0, stream>>>(W1, W2, wt1, wt2);

  dim3 ggrid((NN + 127) / 128, 2);
  // layer 1 (fp32 X input, 3-term split MFMA)
  k_gemm_mfma<<<ggrid, 256, 0, stream>>>(X, wt1, wt1 + 16384, dinv, Hs);
  k_aggregate<<<(NN + 3) / 4, 256, 0, stream>>>((const uint2*)Hs, rows, csr, dinv, b1, (uint2*)A1);
  // layer 2 (bf16 A1 input, 2-term MFMA)
  k_gemm_bf<<<ggrid, 256, 0, stream>>>(A1, wt2, wt2 + 16384, dinv, Hs);
  k_aggregate<<<(NN + 3) / 4, 256, 0, stream>>>((const uint2*)Hs, rows, csr, dinv, b2, (uint2*)A1);

  k_head<<<NG, 256, 0, stream>>>(A1, start, W3, b3, W4, b4, out);
}

// Round 10
// 349.931 us; speedup vs baseline: 1.2200x; 1.0060x over previous
//
#include <hip/hip_runtime.h>

#define NN 100000
#define EE 1600000
#define CH 128
#define NG 512
#define OC 64

// coarse radix partition: 98 buckets of 1024 nodes; fixed-capacity staging cells
#define CSH 10
#define NCB 98
#define PBLK 256
#define PCHUNK 6250     // 256*6250 = 1.6M exactly
#define SCAP 128        // per (block,bucket) cell: mean 63.8 + 8 sigma
#define NCG 8           // cell-groups for k_count2/k_place2 parallelism
#define CPG 32          // cells per group = PBLK/NCG
#define DSL 100352      // deg8 slice stride (covers gid < 98*1024)

// workspace element offsets (4-byte units); total 88.4 MB
#define O_DINV   0
#define O_ROWS   100032   // 100001
#define O_CNT    200064   // 25088
#define O_PART   225152
#define O_OFFS   225280
#define O_START  225408   // 513
#define O_CSR    225984   // padded CSR, cap 2.50M words (sum pdeg <= 2.3M)
#define O_HS     2726016  // bf16 Hs: (NN+1) rows x 128 ushorts = 6400064 words
#define O_STG    9126080  // staging 3.21M words (dead after k_place2)
#define O_WT1    9126080  // split W1 overlays staging: 32768 ushorts
#define O_WT2    9142464
#define O_A1     14800448 // bf16 A1: NN x 128 ushorts = 6.4M words -> ends 21200448
#define O_DEG8   21200448 // 8 x 100352 = 802816 -> ends 22003264
#define O_DEG    22003264 // 100352 -> ends 22103616

typedef __attribute__((ext_vector_type(8))) short short8v;
typedef __attribute__((ext_vector_type(4))) float float4v;

static __device__ __forceinline__ unsigned short f2bf(float x) {
  unsigned u = __float_as_uint(x);
  return (unsigned short)((u + 0x7FFFu + ((u >> 16) & 1u)) >> 16);  // RNE
}
static __device__ __forceinline__ float bf2f(unsigned short h) {
  return __uint_as_float((unsigned)h << 16);
}
static __device__ __forceinline__ unsigned pack2(float a, float b) {
  return (unsigned)f2bf(a) | ((unsigned)f2bf(b) << 16);
}
static __device__ __forceinline__ float bflo(unsigned v) {
  return __uint_as_float(v << 16);
}
static __device__ __forceinline__ float bfhi(unsigned v) {
  return __uint_as_float(v & 0xFFFF0000u);
}

// LDS radix scatter: hist -> scan -> ordered LDS buffer -> contiguous run copies.
__global__ __launch_bounds__(1024) void k_part(const int* __restrict__ src,
                                               const int* __restrict__ dst,
                                               int* __restrict__ cnt,
                                               unsigned* __restrict__ stg) {
  __shared__ int hist[NCB];   // counts, then exclusive bases
  __shared__ int lcur[NCB];
  __shared__ unsigned lout[PCHUNK];
  int t = threadIdx.x;
  int e0 = blockIdx.x * PCHUNK;
  if (t < NCB) { hist[t] = 0; lcur[t] = 0; }
  __syncthreads();
  for (int e = e0 + t; e < e0 + PCHUNK; e += 1024)
    atomicAdd(&hist[dst[e] >> CSH], 1);
  __syncthreads();
  if (t == 0) {
    int s = 0;
    for (int i = 0; i < NCB; ++i) { int v = hist[i]; hist[i] = s; s += v; }
  }
  __syncthreads();
  for (int e = e0 + t; e < e0 + PCHUNK; e += 1024) {
    int d = dst[e];
    int b = d >> CSH;
    int p = hist[b] + atomicAdd(&lcur[b], 1);
    lout[p] = (unsigned)src[e] | ((unsigned)(d & 1023) << 17);
  }
  __syncthreads();
  int w = t >> 6, lane = t & 63;
  unsigned* mystg = stg + (size_t)blockIdx.x * NCB * SCAP;
  for (int b = w; b < NCB; b += 16) {
    int beg = hist[b];
    int end = (b == NCB - 1) ? PCHUNK : hist[b + 1];
    int n = min(end - beg, SCAP);
    for (int i = lane; i < n; i += 64) mystg[b * SCAP + i] = lout[beg + i];
    if (lane == 0) cnt[blockIdx.x * NCB + b] = n;
  }
}

// Per (bucket, cell-group): private degree histogram -> deg8[g][node].
// 784 blocks (was 98) -> ~full CU coverage; all atomics stay in LDS.
__global__ __launch_bounds__(1024) void k_count2(const unsigned* __restrict__ stg,
                                                 const int* __restrict__ cnt,
                                                 int* __restrict__ deg8) {
  __shared__ int ldeg[1024];
  int b = blockIdx.x, g = blockIdx.y;
  int t = threadIdx.x;
  int w = t >> 6, lane = t & 63;
  ldeg[t] = 0;
  __syncthreads();
  for (int blk = g * CPG + w; blk < (g + 1) * CPG; blk += 16) {
    int c = cnt[blk * NCB + b];
    const unsigned* p = stg + ((size_t)blk * NCB + b) * SCAP;
    for (int e = lane; e < c; e += 64) atomicAdd(&ldeg[p[e] >> 17], 1);
  }
  __syncthreads();
  deg8[g * DSL + (b << CSH) + t] = ldeg[t];   // unique owner, plain store
}

// Per bucket: fold deg8 -> deg, dinv; exclusive scan of PADDED degree.
__global__ __launch_bounds__(1024) void k_scan1(const int* __restrict__ deg8,
                                                int* __restrict__ deg,
                                                int* __restrict__ rows,
                                                int* __restrict__ part,
                                                float* __restrict__ dinv) {
  __shared__ int s[1024];
  int b = blockIdx.x, t = threadIdx.x;
  int gid = (b << CSH) + t;
  int v = 0;
#pragma unroll
  for (int g = 0; g < NCG; ++g) v += deg8[g * DSL + gid];
  if (gid < NN) {
    dinv[gid] = rsqrtf((float)(v + 1));  // +1 self-loop (real deg)
    deg[gid] = v;
  }
  int pdeg = (v + 7) & ~7;               // pad to x8 for aggregate; 0 stays 0
  s[t] = pdeg;
  __syncthreads();
  for (int off = 1; off < 1024; off <<= 1) {
    int u = (t >= off) ? s[t - off] : 0;
    __syncthreads();
    if (t >= off) s[t] += u;
    __syncthreads();
  }
  if (gid < NN) rows[gid] = s[t] - pdeg;    // bucket-local exclusive (padded)
  if (t == 1023) part[b] = s[t];            // bucket padded total
}

__global__ void k_scan_part(const int* __restrict__ part, int* __restrict__ offs) {
  __shared__ int s[128];
  int t = threadIdx.x;
  int v = (t < NCB) ? part[t] : 0;
  s[t] = v;
  __syncthreads();
  for (int off = 1; off < 128; off <<= 1) {
    int u = (t >= off) ? s[t - off] : 0;
    __syncthreads();
    if (t >= off) s[t] += u;
    __syncthreads();
  }
  if (t < NCB) offs[t] = s[t] - v;
}

// globalize rows + fused batch-starts + csr pad-fill (disjoint from k_place2).
__global__ void k_scan_add(int* __restrict__ rows, const int* __restrict__ offs,
                           const int* __restrict__ part, const int* __restrict__ deg,
                           const int* __restrict__ batch, int* __restrict__ start,
                           int* __restrict__ csr) {
  int i = blockIdx.x * 256 + threadIdx.x;
  if (i >= NN) return;
  int r = rows[i] + offs[i >> 10];
  rows[i] = r;
  if (i == 0) rows[NN] = offs[NCB - 1] + part[NCB - 1];
  int d = deg[i];
  int pd = (d + 7) & ~7;
  for (int k = r + d; k < r + pd; ++k) csr[k] = NN;  // dummy zero row
  int b = batch[i];
  int prev = (i == 0) ? -1 : batch[i - 1];
  for (int g = prev + 1; g <= b; ++g) start[g] = i;
  if (i == NN - 1)
    for (int g = b + 1; g <= NG; ++g) start[g] = NN;
}

// Per (bucket, cell-group): place srcs via LDS cursors at group-local bases.
// base = rows[node] + sum of earlier groups' counts (group-major edge order —
// order within a row was already arbitrary, only fp32 reassociation).
__global__ __launch_bounds__(1024) void k_place2(const unsigned* __restrict__ stg,
                                                 const int* __restrict__ cnt,
                                                 const int* __restrict__ rows,
                                                 const int* __restrict__ deg8,
                                                 int* __restrict__ csr) {
  __shared__ int lrow[1024];
  __shared__ int lcur[1024];
  int b = blockIdx.x, g = blockIdx.y;
  int t = threadIdx.x;
  int w = t >> 6, lane = t & 63;
  int gid = (b << CSH) + t;
  int base = (gid < NN) ? rows[gid] : 0;
  for (int gp = 0; gp < g; ++gp) base += deg8[gp * DSL + gid];
  lrow[t] = base;
  lcur[t] = 0;
  __syncthreads();
  for (int blk = g * CPG + w; blk < (g + 1) * CPG; blk += 16) {
    int c = cnt[blk * NCB + b];
    const unsigned* p = stg + ((size_t)blk * NCB + b) * SCAP;
    for (int e = lane; e < c; e += 64) {
      unsigned x = p[e];
      int ld = x >> 17;
      int q = atomicAdd(&lcur[ld], 1);
      csr[lrow[ld] + q] = (int)(x & 0x1FFFFu);
    }
  }
}

// split W1,W2 (fp32 [k][n]) into bf16 hi/lo, transposed to [n][k]; one launch.
__global__ void k_wsplit(const float* __restrict__ W1, const float* __restrict__ W2,
                         unsigned short* __restrict__ wt1,
                         unsigned short* __restrict__ wt2) {
  int id = blockIdx.x * 256 + threadIdx.x;   // 32768
  const float* W = (id < 16384) ? W1 : W2;
  unsigned short* wt = (id < 16384) ? wt1 : wt2;
  int i = id & 16383;
  int k = i >> 7, n = i & 127;
  float w = W[i];
  unsigned short h = f2bf(w);
  unsigned short l = f2bf(w - bf2f(h));
  wt[n * 128 + k] = h;
  wt[16384 + n * 128 + k] = l;
}

// Layer-1: Hs(bf16) = diag(dinv) * (X_fp32 @ W) via split-bf16 MFMA (3 terms).
// (782,2) grid, W staged in LDS — verified structure, GEMM stays < 60 us.
__global__ __launch_bounds__(256) void k_gemm_mfma(
    const float* __restrict__ X, const unsigned short* __restrict__ wth,
    const unsigned short* __restrict__ wtl, const float* __restrict__ dinv,
    unsigned short* __restrict__ Hs) {
  __shared__ __align__(16) unsigned short sWh[64 * 136];  // [n][k] pad 136
  __shared__ __align__(16) unsigned short sWl[64 * 136];
  __shared__ __align__(16) unsigned short sXh[128 * 40];  // [row][k-chunk 32] pad 40
  __shared__ __align__(16) unsigned short sXl[128 * 40];

  const int t = threadIdx.x;
  const int w = t >> 6, lane = t & 63;
  const int quad = lane >> 4, lr = lane & 15;
  const int row0 = blockIdx.x * 128;
  const int col0 = blockIdx.y * 64;

  // zero the dummy row NN (read by k_aggregate pad slots)
  if (blockIdx.x == 0 && blockIdx.y == 0 && t < 64)
    *(unsigned*)&Hs[(size_t)NN * CH + t * 2] = 0u;

#pragma unroll
  for (int j = 0; j < 8; ++j) {
    int id = t + j * 256;
    int n = id >> 5, kk = (id & 31) * 4;
    *(ushort4*)&sWh[n * 136 + kk] = *(const ushort4*)&wth[(col0 + n) * 128 + kk];
    *(ushort4*)&sWl[n * 136 + kk] = *(const ushort4*)&wtl[(col0 + n) * 128 + kk];
  }

  float4v acc[2][4];
#pragma unroll
  for (int mi = 0; mi < 2; ++mi)
#pragma unroll
    for (int ni = 0; ni < 4; ++ni) acc[mi][ni] = (float4v){0.f, 0.f, 0.f, 0.f};

  for (int ks = 0; ks < 4; ++ks) {
    const int k0 = ks * 32;
    if (ks) __syncthreads();
#pragma unroll
    for (int i = 0; i < 4; ++i) {
      int row = i * 32 + (t >> 3);
      int seg = t & 7;
      int gr = row0 + row;
      float4 xv = {0.f, 0.f, 0.f, 0.f};
      if (gr < NN) xv = *(const float4*)&X[(size_t)gr * CH + k0 + seg * 4];
      ushort4 h, l;
      h.x = f2bf(xv.x); l.x = f2bf(xv.x - bf2f(h.x));
      h.y = f2bf(xv.y); l.y = f2bf(xv.y - bf2f(h.y));
      h.z = f2bf(xv.z); l.z = f2bf(xv.z - bf2f(h.z));
      h.w = f2bf(xv.w); l.w = f2bf(xv.w - bf2f(h.w));
      *(ushort4*)&sXh[row * 40 + seg * 4] = h;
      *(ushort4*)&sXl[row * 40 + seg * 4] = l;
    }
    __syncthreads();

    short8v ah[2], al[2];
#pragma unroll
    for (int mi = 0; mi < 2; ++mi) {
      int r = w * 32 + mi * 16 + lr;
      ah[mi] = *(const short8v*)&sXh[r * 40 + quad * 8];
      al[mi] = *(const short8v*)&sXl[r * 40 + quad * 8];
    }
#pragma unroll
    for (int ni = 0; ni < 4; ++ni) {
      int n = ni * 16 + lr;
      short8v bh = *(const short8v*)&sWh[n * 136 + k0 + quad * 8];
      short8v bl = *(const short8v*)&sWl[n * 136 + k0 + quad * 8];
#pragma unroll
      for (int mi = 0; mi < 2; ++mi) {
        acc[mi][ni] = __builtin_amdgcn_mfma_f32_16x16x32_bf16(ah[mi], bh, acc[mi][ni], 0, 0, 0);
        acc[mi][ni] = __builtin_amdgcn_mfma_f32_16x16x32_bf16(ah[mi], bl, acc[mi][ni], 0, 0, 0);
        acc[mi][ni] = __builtin_amdgcn_mfma_f32_16x16x32_bf16(al[mi], bh, acc[mi][ni], 0, 0, 0);
      }
    }
  }

#pragma unroll
  for (int mi = 0; mi < 2; ++mi) {
#pragma unroll
    for (int r = 0; r < 4; ++r) {
      int grow = row0 + w * 32 + mi * 16 + quad * 4 + r;
      if (grow < NN) {
        float d = dinv[grow];
#pragma unroll
        for (int ni = 0; ni < 4; ++ni)
          Hs[(size_t)grow * CH + col0 + ni * 16 + lr] = f2bf(d * acc[mi][ni][r]);
      }
    }
  }
}

// Layer-2: Hs(bf16) = diag(dinv) * (A_bf16 @ W). A is exact bf16 (lo=0):
// only 2 MFMA terms (AWh + AWl), no conversion in staging, half the reads.
__global__ __launch_bounds__(256) void k_gemm_bf(
    const unsigned short* __restrict__ A, const unsigned short* __restrict__ wth,
    const unsigned short* __restrict__ wtl, const float* __restrict__ dinv,
    unsigned short* __restrict__ Hs) {
  __shared__ __align__(16) unsigned short sWh[64 * 136];
  __shared__ __align__(16) unsigned short sWl[64 * 136];
  __shared__ __align__(16) unsigned short sA[128 * 40];

  const int t = threadIdx.x;
  const int w = t >> 6, lane = t & 63;
  const int quad = lane >> 4, lr = lane & 15;
  const int row0 = blockIdx.x * 128;
  const int col0 = blockIdx.y * 64;

  if (blockIdx.x == 0 && blockIdx.y == 0 && t < 64)
    *(unsigned*)&Hs[(size_t)NN * CH + t * 2] = 0u;

#pragma unroll
  for (int j = 0; j < 8; ++j) {
    int id = t + j * 256;
    int n = id >> 5, kk = (id & 31) * 4;
    *(ushort4*)&sWh[n * 136 + kk] = *(const ushort4*)&wth[(col0 + n) * 128 + kk];
    *(ushort4*)&sWl[n * 136 + kk] = *(const ushort4*)&wtl[(col0 + n) * 128 + kk];
  }

  float4v acc[2][4];
#pragma unroll
  for (int mi = 0; mi < 2; ++mi)
#pragma unroll
    for (int ni = 0; ni < 4; ++ni) acc[mi][ni] = (float4v){0.f, 0.f, 0.f, 0.f};

  for (int ks = 0; ks < 4; ++ks) {
    const int k0 = ks * 32;
    if (ks) __syncthreads();
    // stage A[row0..row0+127][k0..k0+31] bf16: 8 KB, each thread 2x ushort4
#pragma unroll
    for (int i = 0; i < 2; ++i) {
      int id = t + i * 256;          // 512 ushort4 segments
      int row = id >> 2, seg = id & 3;
      int gr = row0 + row;
      ushort4 v = {0, 0, 0, 0};
      if (gr < NN) v = *(const ushort4*)&A[(size_t)gr * CH + k0 + seg * 8];
      *(ushort4*)&sA[row * 40 + seg * 8] = v;
      ushort4 v2 = {0, 0, 0, 0};
      if (gr < NN) v2 = *(const ushort4*)&A[(size_t)gr * CH + k0 + seg * 8 + 4];
      *(ushort4*)&sA[row * 40 + seg * 8 + 4] = v2;
    }
    __syncthreads();

    short8v ah[2];
#pragma unroll
    for (int mi = 0; mi < 2; ++mi) {
      int r = w * 32 + mi * 16 + lr;
      ah[mi] = *(const short8v*)&sA[r * 40 + quad * 8];
    }
#pragma unroll
    for (int ni = 0; ni < 4; ++ni) {
      int n = ni * 16 + lr;
      short8v bh = *(const short8v*)&sWh[n * 136 + k0 + quad * 8];
      short8v bl = *(const short8v*)&sWl[n * 136 + k0 + quad * 8];
#pragma unroll
      for (int mi = 0; mi < 2; ++mi) {
        acc[mi][ni] = __builtin_amdgcn_mfma_f32_16x16x32_bf16(ah[mi], bh, acc[mi][ni], 0, 0, 0);
        acc[mi][ni] = __builtin_amdgcn_mfma_f32_16x16x32_bf16(ah[mi], bl, acc[mi][ni], 0, 0, 0);
      }
    }
  }

#pragma unroll
  for (int mi = 0; mi < 2; ++mi) {
#pragma unroll
    for (int r = 0; r < 4; ++r) {
      int grow = row0 + w * 32 + mi * 16 + quad * 4 + r;
      if (grow < NN) {
        float d = dinv[grow];
#pragma unroll
        for (int ni = 0; ni < 4; ++ni)
          Hs[(size_t)grow * CH + col0 + ni * 16 + lr] = f2bf(d * acc[mi][ni][r]);
      }
    }
  }
}

// out(bf16)[i] = relu(dinv[i]*(Hs[i] + sum Hs[csr[e]]) + b). One wave per node.
// dwordx2 gathers: lanes 0-31 take even edges, 32-63 odd edges of each 8-group;
// each lane owns 4 channels; one shfl_xor(32) combines halves. (verified 60 us)
__global__ __launch_bounds__(256) void k_aggregate(
    const uint2* __restrict__ H2, const int* __restrict__ rows,
    const int* __restrict__ csr, const float* __restrict__ dinv,
    const float* __restrict__ bias, uint2* __restrict__ out) {
  int node = blockIdx.x * 4 + (threadIdx.x >> 6);
  if (node >= NN) return;
  int lane = threadIdx.x & 63;
  int h = lane >> 5, li = lane & 31;
  float a0 = 0.f, a1 = 0.f, a2 = 0.f, a3 = 0.f;
  int e0 = rows[node], e1 = rows[node + 1];  // padded, multiple of 8
  int nr = (e1 - e0) >> 3;                   // rounds of 8 edges
  if (nr) {
    const int* cp = csr + e0 + h;            // half h reads edges e0+h, e0+h+2, ...
    uint2 va[4], vb[4];

#define LOADQ(buf)                                                          \
  do {                                                                      \
    unsigned s0_ = (unsigned)cp[0], s1_ = (unsigned)cp[2];                  \
    unsigned s2_ = (unsigned)cp[4], s3_ = (unsigned)cp[6];                  \
    buf[0] = H2[(s0_ << 5) | li];                                           \
    buf[1] = H2[(s1_ << 5) | li];                                           \
    buf[2] = H2[(s2_ << 5) | li];                                           \
    buf[3] = H2[(s3_ << 5) | li];                                           \
    cp += 8;                                                                \
  } while (0)

#define ACCQ(buf)                                                           \
  do {                                                                      \
    _Pragma("unroll")                                                       \
    for (int k_ = 0; k_ < 4; ++k_) {                                        \
      a0 += bflo(buf[k_].x); a1 += bfhi(buf[k_].x);                         \
      a2 += bflo(buf[k_].y); a3 += bfhi(buf[k_].y);                         \
    }                                                                       \
  } while (0)

    LOADQ(va);
    int rem = nr - 1;
    while (rem >= 2) {
      LOADQ(vb); ACCQ(va);
      LOADQ(va); ACCQ(vb);
      rem -= 2;
    }
    if (rem) { LOADQ(vb); ACCQ(va); ACCQ(vb); }
    else     { ACCQ(va); }
#undef LOADQ
#undef ACCQ
  }
  // combine even-edge (h=0) and odd-edge (h=1) partial sums
  a0 += __shfl_xor(a0, 32);
  a1 += __shfl_xor(a1, 32);
  a2 += __shfl_xor(a2, 32);
  a3 += __shfl_xor(a3, 32);
  // self-loop term
  uint2 sv = H2[((unsigned)node << 5) | li];
  a0 += bflo(sv.x); a1 += bfhi(sv.x);
  a2 += bflo(sv.y); a3 += bfhi(sv.y);
  float d = dinv[node];
  float4 b4 = *(const float4*)&bias[li << 2];
  float o0 = fmaxf(fmaf(d, a0, b4.x), 0.f);
  float o1 = fmaxf(fmaf(d, a1, b4.y), 0.f);
  float o2 = fmaxf(fmaf(d, a2, b4.z), 0.f);
  float o3 = fmaxf(fmaf(d, a3, b4.w), 0.f);
  if (!h)
    out[((unsigned)node << 5) | li] = make_uint2(pack2(o0, o1), pack2(o2, o3));
}

// Fused per-graph pipeline: segmented mean pool -> MLP1 -> MLP2 -> out.
// Pooling vectorized: short8 (16 B) loads, 16 rows x 16 channel-octets/block.
__global__ __launch_bounds__(256) void k_head(
    const unsigned short* __restrict__ A, const int* __restrict__ start,
    const float* __restrict__ W3, const float* __restrict__ b3,
    const float* __restrict__ W4, const float* __restrict__ b4,
    float* __restrict__ out) {
  __shared__ float ppart[16][128];
  __shared__ float pooled[128];
  __shared__ float g1[128];
  int g = blockIdx.x;
  int t = threadIdx.x;
  int c8 = t & 15;            // channel octet 0..15
  int r = t >> 4;             // row slot 0..15
  int s0 = start[g], s1 = start[g + 1];
  float s[8] = {0.f, 0.f, 0.f, 0.f, 0.f, 0.f, 0.f, 0.f};
  for (int i = s0 + r; i < s1; i += 16) {
    short8v v = *(const short8v*)&A[(size_t)i * CH + c8 * 8];
#pragma unroll
    for (int j = 0; j < 8; ++j) s[j] += bf2f((unsigned short)v[j]);
  }
#pragma unroll
  for (int j = 0; j < 8; ++j) ppart[r][c8 * 8 + j] = s[j];
  __syncthreads();
  if (t < 128) {
    float n = fmaxf((float)(s1 - s0), 1.0f);
    float acc = 0.f;
#pragma unroll
    for (int rr = 0; rr < 16; ++rr) acc += ppart[rr][t];
    pooled[t] = acc / n;
  }
  __syncthreads();
  if (t < 128) {
    float acc = b3[t];
    for (int k = 0; k < 128; ++k) acc += pooled[k] * W3[k * CH + t];
    g1[t] = fmaxf(acc, 0.f);
  }
  __syncthreads();
  if (t < 64) {
    float acc = b4[t];
    for (int k = 0; k < 128; ++k) acc += g1[k] * W4[k * OC + t];
    out[(size_t)g * OC + t] = acc;
  }
}

extern "C" void kernel_launch(void* const* d_in, const int* in_sizes, int n_in,
                              void* d_out, int out_size, void* d_ws, size_t ws_size,
                              hipStream_t stream) {
  const float* X   = (const float*)d_in[0];
  const int* ei    = (const int*)d_in[1];
  const int* batch = (const int*)d_in[2];
  const float* W1  = (const float*)d_in[3];
  const float* b1  = (const float*)d_in[4];
  const float* W2  = (const float*)d_in[5];
  const float* b2  = (const float*)d_in[6];
  const float* W3  = (const float*)d_in[7];
  const float* b3  = (const float*)d_in[8];
  const float* W4  = (const float*)d_in[9];
  const float* b4  = (const float*)d_in[10];
  float* out = (float*)d_out;
  float* ws = (float*)d_ws;

  const int* src = ei;        // edge_index[0]
  const int* dst = ei + EE;   // edge_index[1]

  float* dinv = ws + O_DINV;
  int* rows   = (int*)(ws + O_ROWS);
  int* cnt    = (int*)(ws + O_CNT);
  int* part   = (int*)(ws + O_PART);
  int* offs   = (int*)(ws + O_OFFS);
  int* start  = (int*)(ws + O_START);
  int* csr    = (int*)(ws + O_CSR);
  unsigned short* Hs = (unsigned short*)(ws + O_HS);
  unsigned* stg = (unsigned*)(ws + O_STG);
  unsigned short* wt1 = (unsigned short*)(ws + O_WT1);
  unsigned short* wt2 = (unsigned short*)(ws + O_WT2);
  unsigned short* A1 = (unsigned short*)(ws + O_A1);
  int* deg8   = (int*)(ws + O_DEG8);
  int* deg    = (int*)(ws + O_DEG);

  k_part<<<PBLK, 1024, 0, stream>>>(src, dst, cnt, stg);
  k_count2<<<dim3(NCB, NCG), 1024, 0, stream>>>(stg, cnt, deg8);
  k_scan1<<<NCB, 1024, 0, stream>>>(deg8, deg, rows, part, dinv);
  k_scan_part<<<1, 128, 0, stream>>>(part, offs);
  k_scan_add<<<(NN + 255) / 256, 256, 0, stream>>>(rows, offs, part, deg, batch, start, csr);
  k_place2<<<dim3(NCB, NCG), 1024, 0, stream>>>(stg, cnt, rows, deg8, csr);
  // after k_place2 the staging region is dead; wt1/wt2 overwrite its start
  k_wsplit<<<128, 256, 0, stream>>>(W1, W2, wt1, wt2);

  dim3 ggrid((NN + 127) / 128, 2);
  // layer 1 (fp32 X input, 3-term split MFMA)
  k_gemm_mfma<<<ggrid, 256, 0, stream>>>(X, wt1, wt1 + 16384, dinv, Hs);
  k_aggregate<<<(NN + 3) / 4, 256, 0, stream>>>((const uint2*)Hs, rows, csr, dinv, b1, (uint2*)A1);
  // layer 2 (bf16 A1 input, 2-term MFMA)
  k_gemm_bf<<<ggrid, 256, 0, stream>>>(A1, wt2, wt2 + 16384, dinv, Hs);
  k_aggregate<<<(NN + 3) / 4, 256, 0, stream>>>((const uint2*)Hs, rows, csr, dinv, b2, (uint2*)A1);

  k_head<<<NG, 256, 0, stream>>>(A1, start, W3, b3, W4, b4, out);
}

// Round 11
// 344.945 us; speedup vs baseline: 1.2376x; 1.0145x over previous
//
#include <hip/hip_runtime.h>

#define NN 100000
#define EE 1600000
#define CH 128
#define NG 512
#define OC 64

// coarse radix partition: 98 buckets of 1024 nodes; fixed-capacity staging cells
#define CSH 10
#define NCB 98
#define PBLK 256
#define PCHUNK 6250     // 256*6250 = 1.6M exactly
#define SCAP 128        // per (block,bucket) cell: mean 63.8 + 8 sigma
#define NCG 8           // cell-groups for k_count2/k_place2 parallelism
#define CPG 32          // cells per group = PBLK/NCG
#define DSL 100352      // deg8 slice stride (covers gid < 98*1024)

// workspace element offsets (4-byte units); total 88.5 MB
#define O_DINV   0
#define O_ROWS   100032   // 100001
#define O_CNT    200064   // 25088
#define O_PART   225152
#define O_OFFS   225280
#define O_START  225408   // 513
#define O_CSR    225984   // padded CSR, cap 2.50M words (sum pdeg <= 2.3M)
#define O_HS     2726016  // bf16 Hs: (NN+1) rows x 128 ushorts = 6400064 words
#define O_STG    9126080  // staging 3.21M words (dead after k_place2)
#define O_A1     14800448 // bf16 A1: NN x 128 ushorts = 6.4M words -> ends 21200448
#define O_DEG8   21200448 // 8 x 100352 = 802816 -> ends 22003264
#define O_DEG    22003264 // 100352 -> ends 22103616
#define O_WT1    22103616 // split W1: 32768 ushorts = 16384 words (written by k_scan_add)
#define O_WT2    22120000 // -> ends 22136384

typedef __attribute__((ext_vector_type(8))) short short8v;
typedef __attribute__((ext_vector_type(4))) float float4v;

static __device__ __forceinline__ unsigned short f2bf(float x) {
  unsigned u = __float_as_uint(x);
  return (unsigned short)((u + 0x7FFFu + ((u >> 16) & 1u)) >> 16);  // RNE
}
static __device__ __forceinline__ float bf2f(unsigned short h) {
  return __uint_as_float((unsigned)h << 16);
}
static __device__ __forceinline__ unsigned pack2(float a, float b) {
  return (unsigned)f2bf(a) | ((unsigned)f2bf(b) << 16);
}
static __device__ __forceinline__ float bflo(unsigned v) {
  return __uint_as_float(v << 16);
}
static __device__ __forceinline__ float bfhi(unsigned v) {
  return __uint_as_float(v & 0xFFFF0000u);
}

// LDS radix scatter: hist -> scan -> ordered LDS buffer -> contiguous run copies.
__global__ __launch_bounds__(1024) void k_part(const int* __restrict__ src,
                                               const int* __restrict__ dst,
                                               int* __restrict__ cnt,
                                               unsigned* __restrict__ stg) {
  __shared__ int hist[NCB];   // counts, then exclusive bases
  __shared__ int lcur[NCB];
  __shared__ unsigned lout[PCHUNK];
  int t = threadIdx.x;
  int e0 = blockIdx.x * PCHUNK;
  if (t < NCB) { hist[t] = 0; lcur[t] = 0; }
  __syncthreads();
  for (int e = e0 + t; e < e0 + PCHUNK; e += 1024)
    atomicAdd(&hist[dst[e] >> CSH], 1);
  __syncthreads();
  if (t == 0) {
    int s = 0;
    for (int i = 0; i < NCB; ++i) { int v = hist[i]; hist[i] = s; s += v; }
  }
  __syncthreads();
  for (int e = e0 + t; e < e0 + PCHUNK; e += 1024) {
    int d = dst[e];
    int b = d >> CSH;
    int p = hist[b] + atomicAdd(&lcur[b], 1);
    lout[p] = (unsigned)src[e] | ((unsigned)(d & 1023) << 17);
  }
  __syncthreads();
  int w = t >> 6, lane = t & 63;
  unsigned* mystg = stg + (size_t)blockIdx.x * NCB * SCAP;
  for (int b = w; b < NCB; b += 16) {
    int beg = hist[b];
    int end = (b == NCB - 1) ? PCHUNK : hist[b + 1];
    int n = min(end - beg, SCAP);
    for (int i = lane; i < n; i += 64) mystg[b * SCAP + i] = lout[beg + i];
    if (lane == 0) cnt[blockIdx.x * NCB + b] = n;
  }
}

// Per (bucket, cell-group): private degree histogram -> deg8[g][node].
__global__ __launch_bounds__(1024) void k_count2(const unsigned* __restrict__ stg,
                                                 const int* __restrict__ cnt,
                                                 int* __restrict__ deg8) {
  __shared__ int ldeg[1024];
  int b = blockIdx.x, g = blockIdx.y;
  int t = threadIdx.x;
  int w = t >> 6, lane = t & 63;
  ldeg[t] = 0;
  __syncthreads();
  for (int blk = g * CPG + w; blk < (g + 1) * CPG; blk += 16) {
    int c = cnt[blk * NCB + b];
    const unsigned* p = stg + ((size_t)blk * NCB + b) * SCAP;
    for (int e = lane; e < c; e += 64) atomicAdd(&ldeg[p[e] >> 17], 1);
  }
  __syncthreads();
  deg8[g * DSL + (b << CSH) + t] = ldeg[t];   // unique owner, plain store
}

// Per bucket: fold deg8 -> deg, dinv; exclusive scan of PADDED degree.
__global__ __launch_bounds__(1024) void k_scan1(const int* __restrict__ deg8,
                                                int* __restrict__ deg,
                                                int* __restrict__ rows,
                                                int* __restrict__ part,
                                                float* __restrict__ dinv) {
  __shared__ int s[1024];
  int b = blockIdx.x, t = threadIdx.x;
  int gid = (b << CSH) + t;
  int v = 0;
#pragma unroll
  for (int g = 0; g < NCG; ++g) v += deg8[g * DSL + gid];
  if (gid < NN) {
    dinv[gid] = rsqrtf((float)(v + 1));  // +1 self-loop (real deg)
    deg[gid] = v;
  }
  int pdeg = (v + 7) & ~7;               // pad to x8 for aggregate; 0 stays 0
  s[t] = pdeg;
  __syncthreads();
  for (int off = 1; off < 1024; off <<= 1) {
    int u = (t >= off) ? s[t - off] : 0;
    __syncthreads();
    if (t >= off) s[t] += u;
    __syncthreads();
  }
  if (gid < NN) rows[gid] = s[t] - pdeg;    // bucket-local exclusive (padded)
  if (t == 1023) part[b] = s[t];            // bucket padded total
}

__global__ void k_scan_part(const int* __restrict__ part, int* __restrict__ offs) {
  __shared__ int s[128];
  int t = threadIdx.x;
  int v = (t < NCB) ? part[t] : 0;
  s[t] = v;
  __syncthreads();
  for (int off = 1; off < 128; off <<= 1) {
    int u = (t >= off) ? s[t - off] : 0;
    __syncthreads();
    if (t >= off) s[t] += u;
    __syncthreads();
  }
  if (t < NCB) offs[t] = s[t] - v;
}

// globalize rows + batch-starts + csr pad-fill + fused W1/W2 bf16 hi/lo split.
__global__ void k_scan_add(int* __restrict__ rows, const int* __restrict__ offs,
                           const int* __restrict__ part, const int* __restrict__ deg,
                           const int* __restrict__ batch, int* __restrict__ start,
                           int* __restrict__ csr,
                           const float* __restrict__ W1, const float* __restrict__ W2,
                           unsigned short* __restrict__ wt1,
                           unsigned short* __restrict__ wt2) {
  int i = blockIdx.x * 256 + threadIdx.x;
  if (i >= NN) return;
  if (i < 32768) {             // fused weight split (wt1/wt2 no longer overlay stg)
    const float* W = (i < 16384) ? W1 : W2;
    unsigned short* wt = (i < 16384) ? wt1 : wt2;
    int ii = i & 16383;
    int k = ii >> 7, n = ii & 127;
    float w = W[ii];
    unsigned short h = f2bf(w);
    unsigned short l = f2bf(w - bf2f(h));
    wt[n * 128 + k] = h;
    wt[16384 + n * 128 + k] = l;
  }
  int r = rows[i] + offs[i >> 10];
  rows[i] = r;
  if (i == 0) rows[NN] = offs[NCB - 1] + part[NCB - 1];
  int d = deg[i];
  int pd = (d + 7) & ~7;
  for (int k = r + d; k < r + pd; ++k) csr[k] = NN;  // dummy zero row
  int b = batch[i];
  int prev = (i == 0) ? -1 : batch[i - 1];
  for (int g = prev + 1; g <= b; ++g) start[g] = i;
  if (i == NN - 1)
    for (int g = b + 1; g <= NG; ++g) start[g] = NN;
}

// Per (bucket, cell-group): place srcs via LDS cursors at group-local bases.
__global__ __launch_bounds__(1024) void k_place2(const unsigned* __restrict__ stg,
                                                 const int* __restrict__ cnt,
                                                 const int* __restrict__ rows,
                                                 const int* __restrict__ deg8,
                                                 int* __restrict__ csr) {
  __shared__ int lrow[1024];
  __shared__ int lcur[1024];
  int b = blockIdx.x, g = blockIdx.y;
  int t = threadIdx.x;
  int w = t >> 6, lane = t & 63;
  int gid = (b << CSH) + t;
  int base = (gid < NN) ? rows[gid] : 0;
  for (int gp = 0; gp < g; ++gp) base += deg8[gp * DSL + gid];
  lrow[t] = base;
  lcur[t] = 0;
  __syncthreads();
  for (int blk = g * CPG + w; blk < (g + 1) * CPG; blk += 16) {
    int c = cnt[blk * NCB + b];
    const unsigned* p = stg + ((size_t)blk * NCB + b) * SCAP;
    for (int e = lane; e < c; e += 64) {
      unsigned x = p[e];
      int ld = x >> 17;
      int q = atomicAdd(&lcur[ld], 1);
      csr[lrow[ld] + q] = (int)(x & 0x1FFFFu);
    }
  }
}

// Layer-1: Hs(bf16) = diag(dinv) * (X_fp32 @ W) via split-bf16 MFMA (3 terms).
// (782,2) grid, W staged in LDS — verified structure, GEMM stays < 60 us.
__global__ __launch_bounds__(256) void k_gemm_mfma(
    const float* __restrict__ X, const unsigned short* __restrict__ wth,
    const unsigned short* __restrict__ wtl, const float* __restrict__ dinv,
    unsigned short* __restrict__ Hs) {
  __shared__ __align__(16) unsigned short sWh[64 * 136];  // [n][k] pad 136
  __shared__ __align__(16) unsigned short sWl[64 * 136];
  __shared__ __align__(16) unsigned short sXh[128 * 40];  // [row][k-chunk 32] pad 40
  __shared__ __align__(16) unsigned short sXl[128 * 40];

  const int t = threadIdx.x;
  const int w = t >> 6, lane = t & 63;
  const int quad = lane >> 4, lr = lane & 15;
  const int row0 = blockIdx.x * 128;
  const int col0 = blockIdx.y * 64;

  // zero the dummy row NN (read by k_aggregate pad slots)
  if (blockIdx.x == 0 && blockIdx.y == 0 && t < 64)
    *(unsigned*)&Hs[(size_t)NN * CH + t * 2] = 0u;

#pragma unroll
  for (int j = 0; j < 8; ++j) {
    int id = t + j * 256;
    int n = id >> 5, kk = (id & 31) * 4;
    *(ushort4*)&sWh[n * 136 + kk] = *(const ushort4*)&wth[(col0 + n) * 128 + kk];
    *(ushort4*)&sWl[n * 136 + kk] = *(const ushort4*)&wtl[(col0 + n) * 128 + kk];
  }

  float4v acc[2][4];
#pragma unroll
  for (int mi = 0; mi < 2; ++mi)
#pragma unroll
    for (int ni = 0; ni < 4; ++ni) acc[mi][ni] = (float4v){0.f, 0.f, 0.f, 0.f};

  for (int ks = 0; ks < 4; ++ks) {
    const int k0 = ks * 32;
    if (ks) __syncthreads();
#pragma unroll
    for (int i = 0; i < 4; ++i) {
      int row = i * 32 + (t >> 3);
      int seg = t & 7;
      int gr = row0 + row;
      float4 xv = {0.f, 0.f, 0.f, 0.f};
      if (gr < NN) xv = *(const float4*)&X[(size_t)gr * CH + k0 + seg * 4];
      ushort4 h, l;
      h.x = f2bf(xv.x); l.x = f2bf(xv.x - bf2f(h.x));
      h.y = f2bf(xv.y); l.y = f2bf(xv.y - bf2f(h.y));
      h.z = f2bf(xv.z); l.z = f2bf(xv.z - bf2f(h.z));
      h.w = f2bf(xv.w); l.w = f2bf(xv.w - bf2f(h.w));
      *(ushort4*)&sXh[row * 40 + seg * 4] = h;
      *(ushort4*)&sXl[row * 40 + seg * 4] = l;
    }
    __syncthreads();

    short8v ah[2], al[2];
#pragma unroll
    for (int mi = 0; mi < 2; ++mi) {
      int r = w * 32 + mi * 16 + lr;
      ah[mi] = *(const short8v*)&sXh[r * 40 + quad * 8];
      al[mi] = *(const short8v*)&sXl[r * 40 + quad * 8];
    }
#pragma unroll
    for (int ni = 0; ni < 4; ++ni) {
      int n = ni * 16 + lr;
      short8v bh = *(const short8v*)&sWh[n * 136 + k0 + quad * 8];
      short8v bl = *(const short8v*)&sWl[n * 136 + k0 + quad * 8];
#pragma unroll
      for (int mi = 0; mi < 2; ++mi) {
        acc[mi][ni] = __builtin_amdgcn_mfma_f32_16x16x32_bf16(ah[mi], bh, acc[mi][ni], 0, 0, 0);
        acc[mi][ni] = __builtin_amdgcn_mfma_f32_16x16x32_bf16(ah[mi], bl, acc[mi][ni], 0, 0, 0);
        acc[mi][ni] = __builtin_amdgcn_mfma_f32_16x16x32_bf16(al[mi], bh, acc[mi][ni], 0, 0, 0);
      }
    }
  }

#pragma unroll
  for (int mi = 0; mi < 2; ++mi) {
#pragma unroll
    for (int r = 0; r < 4; ++r) {
      int grow = row0 + w * 32 + mi * 16 + quad * 4 + r;
      if (grow < NN) {
        float d = dinv[grow];
#pragma unroll
        for (int ni = 0; ni < 4; ++ni)
          Hs[(size_t)grow * CH + col0 + ni * 16 + lr] = f2bf(d * acc[mi][ni][r]);
      }
    }
  }
}

// Layer-2: Hs(bf16) = diag(dinv) * (A_bf16 @ W). A exact bf16: 2 MFMA terms.
// MERGED full-width: one block computes all 128 cols (A read ONCE, was 2x);
// W in LDS (80 KB total -> still 2 blocks/CU, same occupancy as split version).
__global__ __launch_bounds__(256) void k_gemm_bf(
    const unsigned short* __restrict__ A, const unsigned short* __restrict__ wth,
    const unsigned short* __restrict__ wtl, const float* __restrict__ dinv,
    unsigned short* __restrict__ Hs) {
  __shared__ __align__(16) unsigned short sWh[128 * 136];
  __shared__ __align__(16) unsigned short sWl[128 * 136];
  __shared__ __align__(16) unsigned short sA[128 * 40];

  const int t = threadIdx.x;
  const int w = t >> 6, lane = t & 63;
  const int quad = lane >> 4, lr = lane & 15;
  const int row0 = blockIdx.x * 128;

  if (blockIdx.x == 0 && t < 64)
    *(unsigned*)&Hs[(size_t)NN * CH + t * 2] = 0u;

#pragma unroll
  for (int j = 0; j < 16; ++j) {
    int id = t + j * 256;
    int n = id >> 5, kk = (id & 31) * 4;
    *(ushort4*)&sWh[n * 136 + kk] = *(const ushort4*)&wth[n * 128 + kk];
    *(ushort4*)&sWl[n * 136 + kk] = *(const ushort4*)&wtl[n * 128 + kk];
  }

  float4v acc[2][8];
#pragma unroll
  for (int mi = 0; mi < 2; ++mi)
#pragma unroll
    for (int ni = 0; ni < 8; ++ni) acc[mi][ni] = (float4v){0.f, 0.f, 0.f, 0.f};

  for (int ks = 0; ks < 4; ++ks) {
    const int k0 = ks * 32;
    if (ks) __syncthreads();
    // stage A[row0..row0+127][k0..k0+31] bf16: 8 KB, each thread 2x ushort4
#pragma unroll
    for (int i = 0; i < 2; ++i) {
      int id = t + i * 256;          // 512 ushort4 segments
      int row = id >> 2, seg = id & 3;
      int gr = row0 + row;
      ushort4 v = {0, 0, 0, 0};
      if (gr < NN) v = *(const ushort4*)&A[(size_t)gr * CH + k0 + seg * 8];
      *(ushort4*)&sA[row * 40 + seg * 8] = v;
      ushort4 v2 = {0, 0, 0, 0};
      if (gr < NN) v2 = *(const ushort4*)&A[(size_t)gr * CH + k0 + seg * 8 + 4];
      *(ushort4*)&sA[row * 40 + seg * 8 + 4] = v2;
    }
    __syncthreads();

    short8v ah[2];
#pragma unroll
    for (int mi = 0; mi < 2; ++mi) {
      int r = w * 32 + mi * 16 + lr;
      ah[mi] = *(const short8v*)&sA[r * 40 + quad * 8];
    }
#pragma unroll
    for (int ni = 0; ni < 8; ++ni) {
      int n = ni * 16 + lr;
      short8v bh = *(const short8v*)&sWh[n * 136 + k0 + quad * 8];
      short8v bl = *(const short8v*)&sWl[n * 136 + k0 + quad * 8];
#pragma unroll
      for (int mi = 0; mi < 2; ++mi) {
        acc[mi][ni] = __builtin_amdgcn_mfma_f32_16x16x32_bf16(ah[mi], bh, acc[mi][ni], 0, 0, 0);
        acc[mi][ni] = __builtin_amdgcn_mfma_f32_16x16x32_bf16(ah[mi], bl, acc[mi][ni], 0, 0, 0);
      }
    }
  }

#pragma unroll
  for (int mi = 0; mi < 2; ++mi) {
#pragma unroll
    for (int r = 0; r < 4; ++r) {
      int grow = row0 + w * 32 + mi * 16 + quad * 4 + r;
      if (grow < NN) {
        float d = dinv[grow];
#pragma unroll
        for (int ni = 0; ni < 8; ++ni)
          Hs[(size_t)grow * CH + ni * 16 + lr] = f2bf(d * acc[mi][ni][r]);
      }
    }
  }
}

// out(bf16)[i] = relu(dinv[i]*(Hs[i] + sum Hs[csr[e]]) + b). One wave per node.
// dwordx2 gathers: lanes 0-31 take even edges, 32-63 odd edges of each 8-group;
// each lane owns 4 channels; one shfl_xor(32) combines halves. (verified 60 us)
__global__ __launch_bounds__(256) void k_aggregate(
    const uint2* __restrict__ H2, const int* __restrict__ rows,
    const int* __restrict__ csr, const float* __restrict__ dinv,
    const float* __restrict__ bias, uint2* __restrict__ out) {
  int node = blockIdx.x * 4 + (threadIdx.x >> 6);
  if (node >= NN) return;
  int lane = threadIdx.x & 63;
  int h = lane >> 5, li = lane & 31;
  float a0 = 0.f, a1 = 0.f, a2 = 0.f, a3 = 0.f;
  int e0 = rows[node], e1 = rows[node + 1];  // padded, multiple of 8
  int nr = (e1 - e0) >> 3;                   // rounds of 8 edges
  if (nr) {
    const int* cp = csr + e0 + h;            // half h reads edges e0+h, e0+h+2, ...
    uint2 va[4], vb[4];

#define LOADQ(buf)                                                          \
  do {                                                                      \
    unsigned s0_ = (unsigned)cp[0], s1_ = (unsigned)cp[2];                  \
    unsigned s2_ = (unsigned)cp[4], s3_ = (unsigned)cp[6];                  \
    buf[0] = H2[(s0_ << 5) | li];                                           \
    buf[1] = H2[(s1_ << 5) | li];                                           \
    buf[2] = H2[(s2_ << 5) | li];                                           \
    buf[3] = H2[(s3_ << 5) | li];                                           \
    cp += 8;                                                                \
  } while (0)

#define ACCQ(buf)                                                           \
  do {                                                                      \
    _Pragma("unroll")                                                       \
    for (int k_ = 0; k_ < 4; ++k_) {                                        \
      a0 += bflo(buf[k_].x); a1 += bfhi(buf[k_].x);                         \
      a2 += bflo(buf[k_].y); a3 += bfhi(buf[k_].y);                         \
    }                                                                       \
  } while (0)

    LOADQ(va);
    int rem = nr - 1;
    while (rem >= 2) {
      LOADQ(vb); ACCQ(va);
      LOADQ(va); ACCQ(vb);
      rem -= 2;
    }
    if (rem) { LOADQ(vb); ACCQ(va); ACCQ(vb); }
    else     { ACCQ(va); }
#undef LOADQ
#undef ACCQ
  }
  // combine even-edge (h=0) and odd-edge (h=1) partial sums
  a0 += __shfl_xor(a0, 32);
  a1 += __shfl_xor(a1, 32);
  a2 += __shfl_xor(a2, 32);
  a3 += __shfl_xor(a3, 32);
  // self-loop term
  uint2 sv = H2[((unsigned)node << 5) | li];
  a0 += bflo(sv.x); a1 += bfhi(sv.x);
  a2 += bflo(sv.y); a3 += bfhi(sv.y);
  float d = dinv[node];
  float4 b4 = *(const float4*)&bias[li << 2];
  float o0 = fmaxf(fmaf(d, a0, b4.x), 0.f);
  float o1 = fmaxf(fmaf(d, a1, b4.y), 0.f);
  float o2 = fmaxf(fmaf(d, a2, b4.z), 0.f);
  float o3 = fmaxf(fmaf(d, a3, b4.w), 0.f);
  if (!h)
    out[((unsigned)node << 5) | li] = make_uint2(pack2(o0, o1), pack2(o2, o3));
}

// Fused per-graph pipeline: segmented mean pool -> MLP1 -> MLP2 -> out.
// Pooling vectorized: short8 (16 B) loads, 16 rows x 16 channel-octets/block.
__global__ __launch_bounds__(256) void k_head(
    const unsigned short* __restrict__ A, const int* __restrict__ start,
    const float* __restrict__ W3, const float* __restrict__ b3,
    const float* __restrict__ W4, const float* __restrict__ b4,
    float* __restrict__ out) {
  __shared__ float ppart[16][128];
  __shared__ float pooled[128];
  __shared__ float g1[128];
  int g = blockIdx.x;
  int t = threadIdx.x;
  int c8 = t & 15;            // channel octet 0..15
  int r = t >> 4;             // row slot 0..15
  int s0 = start[g], s1 = start[g + 1];
  float s[8] = {0.f, 0.f, 0.f, 0.f, 0.f, 0.f, 0.f, 0.f};
  for (int i = s0 + r; i < s1; i += 16) {
    short8v v = *(const short8v*)&A[(size_t)i * CH + c8 * 8];
#pragma unroll
    for (int j = 0; j < 8; ++j) s[j] += bf2f((unsigned short)v[j]);
  }
#pragma unroll
  for (int j = 0; j < 8; ++j) ppart[r][c8 * 8 + j] = s[j];
  __syncthreads();
  if (t < 128) {
    float n = fmaxf((float)(s1 - s0), 1.0f);
    float acc = 0.f;
#pragma unroll
    for (int rr = 0; rr < 16; ++rr) acc += ppart[rr][t];
    pooled[t] = acc / n;
  }
  __syncthreads();
  if (t < 128) {
    float acc = b3[t];
    for (int k = 0; k < 128; ++k) acc += pooled[k] * W3[k * CH + t];
    g1[t] = fmaxf(acc, 0.f);
  }
  __syncthreads();
  if (t < 64) {
    float acc = b4[t];
    for (int k = 0; k < 128; ++k) acc += g1[k] * W4[k * OC + t];
    out[(size_t)g * OC + t] = acc;
  }
}

extern "C" void kernel_launch(void* const* d_in, const int* in_sizes, int n_in,
                              void* d_out, int out_size, void* d_ws, size_t ws_size,
                              hipStream_t stream) {
  const float* X   = (const float*)d_in[0];
  const int* ei    = (const int*)d_in[1];
  const int* batch = (const int*)d_in[2];
  const float* W1  = (const float*)d_in[3];
  const float* b1  = (const float*)d_in[4];
  const float* W2  = (const float*)d_in[5];
  const float* b2  = (const float*)d_in[6];
  const float* W3  = (const float*)d_in[7];
  const float* b3  = (const float*)d_in[8];
  const float* W4  = (const float*)d_in[9];
  const float* b4  = (const float*)d_in[10];
  float* out = (float*)d_out;
  float* ws = (float*)d_ws;

  const int* src = ei;        // edge_index[0]
  const int* dst = ei + EE;   // edge_index[1]

  float* dinv = ws + O_DINV;
  int* rows   = (int*)(ws + O_ROWS);
  int* cnt    = (int*)(ws + O_CNT);
  int* part   = (int*)(ws + O_PART);
  int* offs   = (int*)(ws + O_OFFS);
  int* start  = (int*)(ws + O_START);
  int* csr    = (int*)(ws + O_CSR);
  unsigned short* Hs = (unsigned short*)(ws + O_HS);
  unsigned* stg = (unsigned*)(ws + O_STG);
  unsigned short* wt1 = (unsigned short*)(ws + O_WT1);
  unsigned short* wt2 = (unsigned short*)(ws + O_WT2);
  unsigned short* A1 = (unsigned short*)(ws + O_A1);
  int* deg8   = (int*)(ws + O_DEG8);
  int* deg    = (int*)(ws + O_DEG);

  k_part<<<PBLK, 1024, 0, stream>>>(src, dst, cnt, stg);
  k_count2<<<dim3(NCB, NCG), 1024, 0, stream>>>(stg, cnt, deg8);
  k_scan1<<<NCB, 1024, 0, stream>>>(deg8, deg, rows, part, dinv);
  k_scan_part<<<1, 128, 0, stream>>>(part, offs);
  k_scan_add<<<(NN + 255) / 256, 256, 0, stream>>>(rows, offs, part, deg, batch,
                                                   start, csr, W1, W2, wt1, wt2);
  k_place2<<<dim3(NCB, NCG), 1024, 0, stream>>>(stg, cnt, rows, deg8, csr);

  dim3 ggrid((NN + 127) / 128, 2);
  // layer 1 (fp32 X input, 3-term split MFMA)
  k_gemm_mfma<<<ggrid, 256, 0, stream>>>(X, wt1, wt1 + 16384, dinv, Hs);
  k_aggregate<<<(NN + 3) / 4, 256, 0, stream>>>((const uint2*)Hs, rows, csr, dinv, b1, (uint2*)A1);
  // layer 2 (bf16 A1 input, 2-term MFMA, merged full-width: A read once)
  k_gemm_bf<<<(NN + 127) / 128, 256, 0, stream>>>(A1, wt2, wt2 + 16384, dinv, Hs);
  k_aggregate<<<(NN + 3) / 4, 256, 0, stream>>>((const uint2*)Hs, rows, csr, dinv, b2, (uint2*)A1);

  k_head<<<NG, 256, 0, stream>>>(A1, start, W3, b3, W4, b4, out);
}

// Round 12
// 334.044 us; speedup vs baseline: 1.2780x; 1.0326x over previous
//
#include <hip/hip_runtime.h>

#define NN 100000
#define EE 1600000
#define CH 128
#define NG 512
#define OC 64

// coarse radix partition: 98 buckets of 1024 nodes; fixed-capacity staging cells
#define CSH 10
#define NCB 98
#define PBLK 256
#define PCHUNK 6250     // 256*6250 = 1.6M exactly
#define SCAP 128        // per (block,bucket) cell: mean 63.8 + 8 sigma
#define NCG 8           // cell-groups for k_count2/k_place2 parallelism
#define CPG 32          // cells per group = PBLK/NCG
#define DSL 100352      // deg8 slice stride (covers gid < 98*1024)

// workspace element offsets (4-byte units); total 88.5 MB
#define O_DINV   0
#define O_ROWS   100032   // 100001
#define O_CNT    200064   // 25088
#define O_PART   225152
#define O_START  225408   // 513
#define O_CSR    225984   // padded CSR, cap 2.50M words (sum pdeg <= 2.3M)
#define O_HS     2726016  // bf16 Hs: (NN+1) rows x 128 ushorts = 6400064 words
#define O_STG    9126080  // staging 3.21M words (dead after k_place2)
#define O_A1     14800448 // bf16 A1: NN x 128 ushorts = 6.4M words -> ends 21200448
#define O_DEG8   21200448 // 8 x 100352 = 802816 -> ends 22003264
#define O_DEG    22003264 // 100352 -> ends 22103616
#define O_WT1    22103616 // split W1: 32768 ushorts = 16384 words (by k_scan_add)
#define O_WT2    22120000 // -> ends 22136384

typedef __attribute__((ext_vector_type(8))) short short8v;
typedef __attribute__((ext_vector_type(4))) float float4v;

static __device__ __forceinline__ unsigned short f2bf(float x) {
  unsigned u = __float_as_uint(x);
  return (unsigned short)((u + 0x7FFFu + ((u >> 16) & 1u)) >> 16);  // RNE
}
static __device__ __forceinline__ float bf2f(unsigned short h) {
  return __uint_as_float((unsigned)h << 16);
}
static __device__ __forceinline__ unsigned pack2(float a, float b) {
  return (unsigned)f2bf(a) | ((unsigned)f2bf(b) << 16);
}
static __device__ __forceinline__ float bflo(unsigned v) {
  return __uint_as_float(v << 16);
}
static __device__ __forceinline__ float bfhi(unsigned v) {
  return __uint_as_float(v & 0xFFFF0000u);
}

// LDS radix scatter: hist -> scan -> ordered LDS buffer -> contiguous run copies.
__global__ __launch_bounds__(1024) void k_part(const int* __restrict__ src,
                                               const int* __restrict__ dst,
                                               int* __restrict__ cnt,
                                               unsigned* __restrict__ stg) {
  __shared__ int hist[NCB];   // counts, then exclusive bases
  __shared__ int lcur[NCB];
  __shared__ unsigned lout[PCHUNK];
  int t = threadIdx.x;
  int e0 = blockIdx.x * PCHUNK;
  if (t < NCB) { hist[t] = 0; lcur[t] = 0; }
  __syncthreads();
  for (int e = e0 + t; e < e0 + PCHUNK; e += 1024)
    atomicAdd(&hist[dst[e] >> CSH], 1);
  __syncthreads();
  if (t == 0) {
    int s = 0;
    for (int i = 0; i < NCB; ++i) { int v = hist[i]; hist[i] = s; s += v; }
  }
  __syncthreads();
  for (int e = e0 + t; e < e0 + PCHUNK; e += 1024) {
    int d = dst[e];
    int b = d >> CSH;
    int p = hist[b] + atomicAdd(&lcur[b], 1);
    lout[p] = (unsigned)src[e] | ((unsigned)(d & 1023) << 17);
  }
  __syncthreads();
  int w = t >> 6, lane = t & 63;
  unsigned* mystg = stg + (size_t)blockIdx.x * NCB * SCAP;
  for (int b = w; b < NCB; b += 16) {
    int beg = hist[b];
    int end = (b == NCB - 1) ? PCHUNK : hist[b + 1];
    int n = min(end - beg, SCAP);
    for (int i = lane; i < n; i += 64) mystg[b * SCAP + i] = lout[beg + i];
    if (lane == 0) cnt[blockIdx.x * NCB + b] = n;
  }
}

// Per (bucket, cell-group): private degree histogram -> deg8[g][node].
__global__ __launch_bounds__(1024) void k_count2(const unsigned* __restrict__ stg,
                                                 const int* __restrict__ cnt,
                                                 int* __restrict__ deg8) {
  __shared__ int ldeg[1024];
  int b = blockIdx.x, g = blockIdx.y;
  int t = threadIdx.x;
  int w = t >> 6, lane = t & 63;
  ldeg[t] = 0;
  __syncthreads();
  for (int blk = g * CPG + w; blk < (g + 1) * CPG; blk += 16) {
    int c = cnt[blk * NCB + b];
    const unsigned* p = stg + ((size_t)blk * NCB + b) * SCAP;
    for (int e = lane; e < c; e += 64) atomicAdd(&ldeg[p[e] >> 17], 1);
  }
  __syncthreads();
  deg8[g * DSL + (b << CSH) + t] = ldeg[t];   // unique owner, plain store
}

// Per bucket: fold deg8 -> deg, dinv; exclusive scan of PADDED degree.
__global__ __launch_bounds__(1024) void k_scan1(const int* __restrict__ deg8,
                                                int* __restrict__ deg,
                                                int* __restrict__ rows,
                                                int* __restrict__ part,
                                                float* __restrict__ dinv) {
  __shared__ int s[1024];
  int b = blockIdx.x, t = threadIdx.x;
  int gid = (b << CSH) + t;
  int v = 0;
#pragma unroll
  for (int g = 0; g < NCG; ++g) v += deg8[g * DSL + gid];
  if (gid < NN) {
    dinv[gid] = rsqrtf((float)(v + 1));  // +1 self-loop (real deg)
    deg[gid] = v;
  }
  int pdeg = (v + 7) & ~7;               // pad to x8 for aggregate; 0 stays 0
  s[t] = pdeg;
  __syncthreads();
  for (int off = 1; off < 1024; off <<= 1) {
    int u = (t >= off) ? s[t - off] : 0;
    __syncthreads();
    if (t >= off) s[t] += u;
    __syncthreads();
  }
  if (gid < NN) rows[gid] = s[t] - pdeg;    // bucket-local exclusive (padded)
  if (t == 1023) part[b] = s[t];            // bucket padded total
}

// globalize rows (prefix over part computed in-block; k_scan_part eliminated)
// + batch-starts + csr pad-fill + fused W1/W2 bf16 hi/lo split.
__global__ __launch_bounds__(256) void k_scan_add(
    int* __restrict__ rows, const int* __restrict__ part,
    const int* __restrict__ deg, const int* __restrict__ batch,
    int* __restrict__ start, int* __restrict__ csr,
    const float* __restrict__ W1, const float* __restrict__ W2,
    unsigned short* __restrict__ wt1, unsigned short* __restrict__ wt2) {
  __shared__ int red[256];
  int bkt = blockIdx.x >> 2;           // all 256 nodes of a block share a bucket
  int partial = 0;
  for (int j = threadIdx.x; j < bkt; j += 256) partial += part[j];
  red[threadIdx.x] = partial;
  __syncthreads();
  for (int off = 128; off; off >>= 1) {
    if (threadIdx.x < off) red[threadIdx.x] += red[threadIdx.x + off];
    __syncthreads();
  }
  int boff = red[0];
  int i = blockIdx.x * 256 + threadIdx.x;
  if (i >= NN) return;
  if (i < 32768) {             // fused weight split
    const float* W = (i < 16384) ? W1 : W2;
    unsigned short* wt = (i < 16384) ? wt1 : wt2;
    int ii = i & 16383;
    int k = ii >> 7, n = ii & 127;
    float w = W[ii];
    unsigned short h = f2bf(w);
    unsigned short l = f2bf(w - bf2f(h));
    wt[n * 128 + k] = h;
    wt[16384 + n * 128 + k] = l;
  }
  int r = rows[i] + boff;
  rows[i] = r;
  if (blockIdx.x == 390 && threadIdx.x == 0)
    rows[NN] = boff + part[NCB - 1];   // bkt==97 here: total padded edges
  int d = deg[i];
  int pd = (d + 7) & ~7;
  for (int k = r + d; k < r + pd; ++k) csr[k] = NN;  // dummy zero row
  int b = batch[i];
  int prev = (i == 0) ? -1 : batch[i - 1];
  for (int g = prev + 1; g <= b; ++g) start[g] = i;
  if (i == NN - 1)
    for (int g = b + 1; g <= NG; ++g) start[g] = NN;
}

// Per (bucket, cell-group): place srcs via LDS cursors at group-local bases.
__global__ __launch_bounds__(1024) void k_place2(const unsigned* __restrict__ stg,
                                                 const int* __restrict__ cnt,
                                                 const int* __restrict__ rows,
                                                 const int* __restrict__ deg8,
                                                 int* __restrict__ csr) {
  __shared__ int lrow[1024];
  __shared__ int lcur[1024];
  int b = blockIdx.x, g = blockIdx.y;
  int t = threadIdx.x;
  int w = t >> 6, lane = t & 63;
  int gid = (b << CSH) + t;
  int base = (gid < NN) ? rows[gid] : 0;
  for (int gp = 0; gp < g; ++gp) base += deg8[gp * DSL + gid];
  lrow[t] = base;
  lcur[t] = 0;
  __syncthreads();
  for (int blk = g * CPG + w; blk < (g + 1) * CPG; blk += 16) {
    int c = cnt[blk * NCB + b];
    const unsigned* p = stg + ((size_t)blk * NCB + b) * SCAP;
    for (int e = lane; e < c; e += 64) {
      unsigned x = p[e];
      int ld = x >> 17;
      int q = atomicAdd(&lcur[ld], 1);
      csr[lrow[ld] + q] = (int)(x & 0x1FFFFu);
    }
  }
}

// Layer-1: Hs(bf16) = diag(dinv) * (X_fp32 @ W), split-bf16 MFMA (3 terms).
// MERGED full-width, 512 threads: X read ONCE (was 2x); W hi/lo in LDS
// (90 KB -> 1 block/CU x 8 waves = same 8 waves/CU as the split config).
__global__ __launch_bounds__(512) void k_gemm_mfma(
    const float* __restrict__ X, const unsigned short* __restrict__ wth,
    const unsigned short* __restrict__ wtl, const float* __restrict__ dinv,
    unsigned short* __restrict__ Hs) {
  __shared__ __align__(16) unsigned short sWh[128 * 136];  // [n][k] pad 136
  __shared__ __align__(16) unsigned short sWl[128 * 136];
  __shared__ __align__(16) unsigned short sXh[128 * 40];   // [row][k-chunk 32]
  __shared__ __align__(16) unsigned short sXl[128 * 40];

  const int t = threadIdx.x;
  const int w = t >> 6, lane = t & 63;
  const int quad = lane >> 4, lr = lane & 15;
  const int wr = w & 3, wc = w >> 2;     // wave row-group 0..3, col-half 0..1
  const int row0 = blockIdx.x * 128;

  // zero the dummy row NN (read by k_aggregate pad slots)
  if (blockIdx.x == 0 && t < 64)
    *(unsigned*)&Hs[(size_t)NN * CH + t * 2] = 0u;

#pragma unroll
  for (int j = 0; j < 8; ++j) {
    int id = t + j * 512;
    int n = id >> 5, kk = (id & 31) * 4;
    *(ushort4*)&sWh[n * 136 + kk] = *(const ushort4*)&wth[n * 128 + kk];
    *(ushort4*)&sWl[n * 136 + kk] = *(const ushort4*)&wtl[n * 128 + kk];
  }

  float4v acc[2][4];
#pragma unroll
  for (int mi = 0; mi < 2; ++mi)
#pragma unroll
    for (int ni = 0; ni < 4; ++ni) acc[mi][ni] = (float4v){0.f, 0.f, 0.f, 0.f};

  for (int ks = 0; ks < 4; ++ks) {
    const int k0 = ks * 32;
    if (ks) __syncthreads();
#pragma unroll
    for (int i = 0; i < 2; ++i) {
      int row = i * 64 + (t >> 3);
      int seg = t & 7;
      int gr = row0 + row;
      float4 xv = {0.f, 0.f, 0.f, 0.f};
      if (gr < NN) xv = *(const float4*)&X[(size_t)gr * CH + k0 + seg * 4];
      ushort4 h, l;
      h.x = f2bf(xv.x); l.x = f2bf(xv.x - bf2f(h.x));
      h.y = f2bf(xv.y); l.y = f2bf(xv.y - bf2f(h.y));
      h.z = f2bf(xv.z); l.z = f2bf(xv.z - bf2f(h.z));
      h.w = f2bf(xv.w); l.w = f2bf(xv.w - bf2f(h.w));
      *(ushort4*)&sXh[row * 40 + seg * 4] = h;
      *(ushort4*)&sXl[row * 40 + seg * 4] = l;
    }
    __syncthreads();

    short8v ah[2], al[2];
#pragma unroll
    for (int mi = 0; mi < 2; ++mi) {
      int r = wr * 32 + mi * 16 + lr;
      ah[mi] = *(const short8v*)&sXh[r * 40 + quad * 8];
      al[mi] = *(const short8v*)&sXl[r * 40 + quad * 8];
    }
#pragma unroll
    for (int ni = 0; ni < 4; ++ni) {
      int n = wc * 64 + ni * 16 + lr;
      short8v bh = *(const short8v*)&sWh[n * 136 + k0 + quad * 8];
      short8v bl = *(const short8v*)&sWl[n * 136 + k0 + quad * 8];
#pragma unroll
      for (int mi = 0; mi < 2; ++mi) {
        acc[mi][ni] = __builtin_amdgcn_mfma_f32_16x16x32_bf16(ah[mi], bh, acc[mi][ni], 0, 0, 0);
        acc[mi][ni] = __builtin_amdgcn_mfma_f32_16x16x32_bf16(ah[mi], bl, acc[mi][ni], 0, 0, 0);
        acc[mi][ni] = __builtin_amdgcn_mfma_f32_16x16x32_bf16(al[mi], bh, acc[mi][ni], 0, 0, 0);
      }
    }
  }

#pragma unroll
  for (int mi = 0; mi < 2; ++mi) {
#pragma unroll
    for (int r = 0; r < 4; ++r) {
      int grow = row0 + wr * 32 + mi * 16 + quad * 4 + r;
      if (grow < NN) {
        float d = dinv[grow];
#pragma unroll
        for (int ni = 0; ni < 4; ++ni)
          Hs[(size_t)grow * CH + wc * 64 + ni * 16 + lr] = f2bf(d * acc[mi][ni][r]);
      }
    }
  }
}

// Layer-2: Hs(bf16) = diag(dinv) * (A_bf16 @ W). A exact bf16: 2 MFMA terms.
// MERGED full-width (verified r11): A read once, W in LDS, 2 blocks/CU.
__global__ __launch_bounds__(256) void k_gemm_bf(
    const unsigned short* __restrict__ A, const unsigned short* __restrict__ wth,
    const unsigned short* __restrict__ wtl, const float* __restrict__ dinv,
    unsigned short* __restrict__ Hs) {
  __shared__ __align__(16) unsigned short sWh[128 * 136];
  __shared__ __align__(16) unsigned short sWl[128 * 136];
  __shared__ __align__(16) unsigned short sA[128 * 40];

  const int t = threadIdx.x;
  const int w = t >> 6, lane = t & 63;
  const int quad = lane >> 4, lr = lane & 15;
  const int row0 = blockIdx.x * 128;

  if (blockIdx.x == 0 && t < 64)
    *(unsigned*)&Hs[(size_t)NN * CH + t * 2] = 0u;

#pragma unroll
  for (int j = 0; j < 16; ++j) {
    int id = t + j * 256;
    int n = id >> 5, kk = (id & 31) * 4;
    *(ushort4*)&sWh[n * 136 + kk] = *(const ushort4*)&wth[n * 128 + kk];
    *(ushort4*)&sWl[n * 136 + kk] = *(const ushort4*)&wtl[n * 128 + kk];
  }

  float4v acc[2][8];
#pragma unroll
  for (int mi = 0; mi < 2; ++mi)
#pragma unroll
    for (int ni = 0; ni < 8; ++ni) acc[mi][ni] = (float4v){0.f, 0.f, 0.f, 0.f};

  for (int ks = 0; ks < 4; ++ks) {
    const int k0 = ks * 32;
    if (ks) __syncthreads();
    // stage A[row0..row0+127][k0..k0+31] bf16: 8 KB, each thread 2x ushort4
#pragma unroll
    for (int i = 0; i < 2; ++i) {
      int id = t + i * 256;          // 512 ushort4 segments
      int row = id >> 2, seg = id & 3;
      int gr = row0 + row;
      ushort4 v = {0, 0, 0, 0};
      if (gr < NN) v = *(const ushort4*)&A[(size_t)gr * CH + k0 + seg * 8];
      *(ushort4*)&sA[row * 40 + seg * 8] = v;
      ushort4 v2 = {0, 0, 0, 0};
      if (gr < NN) v2 = *(const ushort4*)&A[(size_t)gr * CH + k0 + seg * 8 + 4];
      *(ushort4*)&sA[row * 40 + seg * 8 + 4] = v2;
    }
    __syncthreads();

    short8v ah[2];
#pragma unroll
    for (int mi = 0; mi < 2; ++mi) {
      int r = w * 32 + mi * 16 + lr;
      ah[mi] = *(const short8v*)&sA[r * 40 + quad * 8];
    }
#pragma unroll
    for (int ni = 0; ni < 8; ++ni) {
      int n = ni * 16 + lr;
      short8v bh = *(const short8v*)&sWh[n * 136 + k0 + quad * 8];
      short8v bl = *(const short8v*)&sWl[n * 136 + k0 + quad * 8];
#pragma unroll
      for (int mi = 0; mi < 2; ++mi) {
        acc[mi][ni] = __builtin_amdgcn_mfma_f32_16x16x32_bf16(ah[mi], bh, acc[mi][ni], 0, 0, 0);
        acc[mi][ni] = __builtin_amdgcn_mfma_f32_16x16x32_bf16(ah[mi], bl, acc[mi][ni], 0, 0, 0);
      }
    }
  }

#pragma unroll
  for (int mi = 0; mi < 2; ++mi) {
#pragma unroll
    for (int r = 0; r < 4; ++r) {
      int grow = row0 + w * 32 + mi * 16 + quad * 4 + r;
      if (grow < NN) {
        float d = dinv[grow];
#pragma unroll
        for (int ni = 0; ni < 8; ++ni)
          Hs[(size_t)grow * CH + ni * 16 + lr] = f2bf(d * acc[mi][ni][r]);
      }
    }
  }
}

// out(bf16)[i] = relu(dinv[i]*(Hs[i] + sum Hs[csr[e]]) + b). One wave per node.
// dwordx2 gathers: lanes 0-31 take even edges, 32-63 odd edges of each 8-group;
// each lane owns 4 channels; one shfl_xor(32) combines halves. (verified 60 us)
__global__ __launch_bounds__(256) void k_aggregate(
    const uint2* __restrict__ H2, const int* __restrict__ rows,
    const int* __restrict__ csr, const float* __restrict__ dinv,
    const float* __restrict__ bias, uint2* __restrict__ out) {
  int node = blockIdx.x * 4 + (threadIdx.x >> 6);
  if (node >= NN) return;
  int lane = threadIdx.x & 63;
  int h = lane >> 5, li = lane & 31;
  float a0 = 0.f, a1 = 0.f, a2 = 0.f, a3 = 0.f;
  int e0 = rows[node], e1 = rows[node + 1];  // padded, multiple of 8
  int nr = (e1 - e0) >> 3;                   // rounds of 8 edges
  if (nr) {
    const int* cp = csr + e0 + h;            // half h reads edges e0+h, e0+h+2, ...
    uint2 va[4], vb[4];

#define LOADQ(buf)                                                          \
  do {                                                                      \
    unsigned s0_ = (unsigned)cp[0], s1_ = (unsigned)cp[2];                  \
    unsigned s2_ = (unsigned)cp[4], s3_ = (unsigned)cp[6];                  \
    buf[0] = H2[(s0_ << 5) | li];                                           \
    buf[1] = H2[(s1_ << 5) | li];                                           \
    buf[2] = H2[(s2_ << 5) | li];                                           \
    buf[3] = H2[(s3_ << 5) | li];                                           \
    cp += 8;                                                                \
  } while (0)

#define ACCQ(buf)                                                           \
  do {                                                                      \
    _Pragma("unroll")                                                       \
    for (int k_ = 0; k_ < 4; ++k_) {                                        \
      a0 += bflo(buf[k_].x); a1 += bfhi(buf[k_].x);                         \
      a2 += bflo(buf[k_].y); a3 += bfhi(buf[k_].y);                         \
    }                                                                       \
  } while (0)

    LOADQ(va);
    int rem = nr - 1;
    while (rem >= 2) {
      LOADQ(vb); ACCQ(va);
      LOADQ(va); ACCQ(vb);
      rem -= 2;
    }
    if (rem) { LOADQ(vb); ACCQ(va); ACCQ(vb); }
    else     { ACCQ(va); }
#undef LOADQ
#undef ACCQ
  }
  // combine even-edge (h=0) and odd-edge (h=1) partial sums
  a0 += __shfl_xor(a0, 32);
  a1 += __shfl_xor(a1, 32);
  a2 += __shfl_xor(a2, 32);
  a3 += __shfl_xor(a3, 32);
  // self-loop term
  uint2 sv = H2[((unsigned)node << 5) | li];
  a0 += bflo(sv.x); a1 += bfhi(sv.x);
  a2 += bflo(sv.y); a3 += bfhi(sv.y);
  float d = dinv[node];
  float4 b4 = *(const float4*)&bias[li << 2];
  float o0 = fmaxf(fmaf(d, a0, b4.x), 0.f);
  float o1 = fmaxf(fmaf(d, a1, b4.y), 0.f);
  float o2 = fmaxf(fmaf(d, a2, b4.z), 0.f);
  float o3 = fmaxf(fmaf(d, a3, b4.w), 0.f);
  if (!h)
    out[((unsigned)node << 5) | li] = make_uint2(pack2(o0, o1), pack2(o2, o3));
}

// Fused per-graph pipeline: segmented mean pool -> MLP1 -> MLP2 -> out.
// Pooling vectorized: short8 (16 B) loads, 16 rows x 16 channel-octets/block.
__global__ __launch_bounds__(256) void k_head(
    const unsigned short* __restrict__ A, const int* __restrict__ start,
    const float* __restrict__ W3, const float* __restrict__ b3,
    const float* __restrict__ W4, const float* __restrict__ b4,
    float* __restrict__ out) {
  __shared__ float ppart[16][128];
  __shared__ float pooled[128];
  __shared__ float g1[128];
  int g = blockIdx.x;
  int t = threadIdx.x;
  int c8 = t & 15;            // channel octet 0..15
  int r = t >> 4;             // row slot 0..15
  int s0 = start[g], s1 = start[g + 1];
  float s[8] = {0.f, 0.f, 0.f, 0.f, 0.f, 0.f, 0.f, 0.f};
  for (int i = s0 + r; i < s1; i += 16) {
    short8v v = *(const short8v*)&A[(size_t)i * CH + c8 * 8];
#pragma unroll
    for (int j = 0; j < 8; ++j) s[j] += bf2f((unsigned short)v[j]);
  }
#pragma unroll
  for (int j = 0; j < 8; ++j) ppart[r][c8 * 8 + j] = s[j];
  __syncthreads();
  if (t < 128) {
    float n = fmaxf((float)(s1 - s0), 1.0f);
    float acc = 0.f;
#pragma unroll
    for (int rr = 0; rr < 16; ++rr) acc += ppart[rr][t];
    pooled[t] = acc / n;
  }
  __syncthreads();
  if (t < 128) {
    float acc = b3[t];
    for (int k = 0; k < 128; ++k) acc += pooled[k] * W3[k * CH + t];
    g1[t] = fmaxf(acc, 0.f);
  }
  __syncthreads();
  if (t < 64) {
    float acc = b4[t];
    for (int k = 0; k < 128; ++k) acc += g1[k] * W4[k * OC + t];
    out[(size_t)g * OC + t] = acc;
  }
}

extern "C" void kernel_launch(void* const* d_in, const int* in_sizes, int n_in,
                              void* d_out, int out_size, void* d_ws, size_t ws_size,
                              hipStream_t stream) {
  const float* X   = (const float*)d_in[0];
  const int* ei    = (const int*)d_in[1];
  const int* batch = (const int*)d_in[2];
  const float* W1  = (const float*)d_in[3];
  const float* b1  = (const float*)d_in[4];
  const float* W2  = (const float*)d_in[5];
  const float* b2  = (const float*)d_in[6];
  const float* W3  = (const float*)d_in[7];
  const float* b3  = (const float*)d_in[8];
  const float* W4  = (const float*)d_in[9];
  const float* b4  = (const float*)d_in[10];
  float* out = (float*)d_out;
  float* ws = (float*)d_ws;

  const int* src = ei;        // edge_index[0]
  const int* dst = ei + EE;   // edge_index[1]

  float* dinv = ws + O_DINV;
  int* rows   = (int*)(ws + O_ROWS);
  int* cnt    = (int*)(ws + O_CNT);
  int* part   = (int*)(ws + O_PART);
  int* start  = (int*)(ws + O_START);
  int* csr    = (int*)(ws + O_CSR);
  unsigned short* Hs = (unsigned short*)(ws + O_HS);
  unsigned* stg = (unsigned*)(ws + O_STG);
  unsigned short* wt1 = (unsigned short*)(ws + O_WT1);
  unsigned short* wt2 = (unsigned short*)(ws + O_WT2);
  unsigned short* A1 = (unsigned short*)(ws + O_A1);
  int* deg8   = (int*)(ws + O_DEG8);
  int* deg    = (int*)(ws + O_DEG);

  k_part<<<PBLK, 1024, 0, stream>>>(src, dst, cnt, stg);
  k_count2<<<dim3(NCB, NCG), 1024, 0, stream>>>(stg, cnt, deg8);
  k_scan1<<<NCB, 1024, 0, stream>>>(deg8, deg, rows, part, dinv);
  k_scan_add<<<(NN + 255) / 256, 256, 0, stream>>>(rows, part, deg, batch,
                                                   start, csr, W1, W2, wt1, wt2);
  k_place2<<<dim3(NCB, NCG), 1024, 0, stream>>>(stg, cnt, rows, deg8, csr);

  // layer 1 (fp32 X input, 3-term split MFMA, merged full-width: X read once)
  k_gemm_mfma<<<(NN + 127) / 128, 512, 0, stream>>>(X, wt1, wt1 + 16384, dinv, Hs);
  k_aggregate<<<(NN + 3) / 4, 256, 0, stream>>>((const uint2*)Hs, rows, csr, dinv, b1, (uint2*)A1);
  // layer 2 (bf16 A1 input, 2-term MFMA, merged full-width: A read once)
  k_gemm_bf<<<(NN + 127) / 128, 256, 0, stream>>>(A1, wt2, wt2 + 16384, dinv, Hs);
  k_aggregate<<<(NN + 3) / 4, 256, 0, stream>>>((const uint2*)Hs, rows, csr, dinv, b2, (uint2*)A1);

  k_head<<<NG, 256, 0, stream>>>(A1, start, W3, b3, W4, b4, out);
}

// Round 13
// 333.306 us; speedup vs baseline: 1.2808x; 1.0022x over previous
//
#include <hip/hip_runtime.h>

#define NN 100000
#define EE 1600000
#define CH 128
#define NG 512
#define OC 64

// coarse radix partition: 98 buckets of 1024 nodes; fixed-capacity staging cells
#define CSH 10
#define NCB 98
#define PBLK 256
#define PCHUNK 6250     // 256*6250 = 1.6M exactly
#define SCAP 128        // per (block,bucket) cell: mean 63.8 + 8 sigma
#define NCG 8           // cell-groups for k_count2/k_place2 parallelism
#define CPG 32          // cells per group = PBLK/NCG
#define DSL 100352      // deg8 slice stride (covers gid < 98*1024)

// workspace element offsets (4-byte units); total 88.5 MB
#define O_DINV   0
#define O_ROWS   100032   // 100001
#define O_CNT    200064   // 25088
#define O_PART   225152
#define O_START  225408   // 513
#define O_CSR    225984   // padded CSR, cap 2.50M words (sum pdeg <= 2.3M)
#define O_HS     2726016  // bf16 Hs: (NN+1) rows x 128 ushorts = 6400064 words
#define O_STG    9126080  // staging 3.21M words (dead after k_place2)
#define O_A1     14800448 // bf16 A1: NN x 128 ushorts = 6.4M words -> ends 21200448
#define O_DEG8   21200448 // 8 x 100352 = 802816 -> ends 22003264
#define O_DEG    22003264 // 100352 -> ends 22103616
#define O_WT1    22103616 // split W1: 32768 ushorts = 16384 words (by k_scan_add)
#define O_WT2    22120000 // -> ends 22136384

typedef __attribute__((ext_vector_type(8))) short short8v;
typedef __attribute__((ext_vector_type(4))) float float4v;

static __device__ __forceinline__ unsigned short f2bf(float x) {
  unsigned u = __float_as_uint(x);
  return (unsigned short)((u + 0x7FFFu + ((u >> 16) & 1u)) >> 16);  // RNE
}
static __device__ __forceinline__ float bf2f(unsigned short h) {
  return __uint_as_float((unsigned)h << 16);
}
static __device__ __forceinline__ unsigned pack2(float a, float b) {
  return (unsigned)f2bf(a) | ((unsigned)f2bf(b) << 16);
}
static __device__ __forceinline__ float bflo(unsigned v) {
  return __uint_as_float(v << 16);
}
static __device__ __forceinline__ float bfhi(unsigned v) {
  return __uint_as_float(v & 0xFFFF0000u);
}

// LDS radix scatter with 4-way sub-histograms: thread-group g=t>>8 owns a
// private count/cursor array -> ~4x less LDS-atomic serialization on both
// the histogram pass and the scatter pass. Bucket-run edge order becomes
// group-major (was arbitrary atomic order anyway).
__global__ __launch_bounds__(1024) void k_part(const int* __restrict__ src,
                                               const int* __restrict__ dst,
                                               int* __restrict__ cnt,
                                               unsigned* __restrict__ stg) {
  __shared__ int hist[NCB];        // exclusive bucket bases (then run bounds)
  __shared__ int lhist[4 * NCB];   // per-group counts, then per-group cursors
  __shared__ unsigned lout[PCHUNK];
  int t = threadIdx.x;
  int g = t >> 8;                  // sub-histogram group 0..3
  int e0 = blockIdx.x * PCHUNK;
  if (t < 4 * NCB) lhist[t] = 0;
  __syncthreads();
  for (int e = e0 + t; e < e0 + PCHUNK; e += 1024)
    atomicAdd(&lhist[g * NCB + (dst[e] >> CSH)], 1);
  __syncthreads();
  int c0 = 0, c1 = 0, c2 = 0, c3 = 0;
  if (t < NCB) {
    c0 = lhist[0 * NCB + t];
    c1 = lhist[1 * NCB + t];
    c2 = lhist[2 * NCB + t];
    c3 = lhist[3 * NCB + t];
    hist[t] = c0 + c1 + c2 + c3;   // bucket total (temporarily)
  }
  __syncthreads();
  if (t == 0) {
    int s = 0;
    for (int i = 0; i < NCB; ++i) { int v = hist[i]; hist[i] = s; s += v; }
  }
  __syncthreads();
  if (t < NCB) {                   // seed per-group cursors
    int base = hist[t];
    lhist[0 * NCB + t] = base;
    lhist[1 * NCB + t] = base + c0;
    lhist[2 * NCB + t] = base + c0 + c1;
    lhist[3 * NCB + t] = base + c0 + c1 + c2;
  }
  __syncthreads();
  for (int e = e0 + t; e < e0 + PCHUNK; e += 1024) {
    int d = dst[e];
    int b = d >> CSH;
    int p = atomicAdd(&lhist[g * NCB + b], 1);
    lout[p] = (unsigned)src[e] | ((unsigned)(d & 1023) << 17);
  }
  __syncthreads();
  int w = t >> 6, lane = t & 63;
  unsigned* mystg = stg + (size_t)blockIdx.x * NCB * SCAP;
  for (int b = w; b < NCB; b += 16) {
    int beg = hist[b];
    int end = (b == NCB - 1) ? PCHUNK : hist[b + 1];
    int n = min(end - beg, SCAP);
    for (int i = lane; i < n; i += 64) mystg[b * SCAP + i] = lout[beg + i];
    if (lane == 0) cnt[blockIdx.x * NCB + b] = n;
  }
}

// Per (bucket, cell-group): private degree histogram -> deg8[g][node].
__global__ __launch_bounds__(1024) void k_count2(const unsigned* __restrict__ stg,
                                                 const int* __restrict__ cnt,
                                                 int* __restrict__ deg8) {
  __shared__ int ldeg[1024];
  int b = blockIdx.x, g = blockIdx.y;
  int t = threadIdx.x;
  int w = t >> 6, lane = t & 63;
  ldeg[t] = 0;
  __syncthreads();
  for (int blk = g * CPG + w; blk < (g + 1) * CPG; blk += 16) {
    int c = cnt[blk * NCB + b];
    const unsigned* p = stg + ((size_t)blk * NCB + b) * SCAP;
    for (int e = lane; e < c; e += 64) atomicAdd(&ldeg[p[e] >> 17], 1);
  }
  __syncthreads();
  deg8[g * DSL + (b << CSH) + t] = ldeg[t];   // unique owner, plain store
}

// Per bucket: fold deg8 -> deg, dinv; exclusive scan of PADDED degree.
__global__ __launch_bounds__(1024) void k_scan1(const int* __restrict__ deg8,
                                                int* __restrict__ deg,
                                                int* __restrict__ rows,
                                                int* __restrict__ part,
                                                float* __restrict__ dinv) {
  __shared__ int s[1024];
  int b = blockIdx.x, t = threadIdx.x;
  int gid = (b << CSH) + t;
  int v = 0;
#pragma unroll
  for (int g = 0; g < NCG; ++g) v += deg8[g * DSL + gid];
  if (gid < NN) {
    dinv[gid] = rsqrtf((float)(v + 1));  // +1 self-loop (real deg)
    deg[gid] = v;
  }
  int pdeg = (v + 7) & ~7;               // pad to x8 for aggregate; 0 stays 0
  s[t] = pdeg;
  __syncthreads();
  for (int off = 1; off < 1024; off <<= 1) {
    int u = (t >= off) ? s[t - off] : 0;
    __syncthreads();
    if (t >= off) s[t] += u;
    __syncthreads();
  }
  if (gid < NN) rows[gid] = s[t] - pdeg;    // bucket-local exclusive (padded)
  if (t == 1023) part[b] = s[t];            // bucket padded total
}

// globalize rows (prefix over part computed in-block; no k_scan_part launch)
// + batch-starts + csr pad-fill + fused W1/W2 bf16 hi/lo split.
__global__ __launch_bounds__(256) void k_scan_add(
    int* __restrict__ rows, const int* __restrict__ part,
    const int* __restrict__ deg, const int* __restrict__ batch,
    int* __restrict__ start, int* __restrict__ csr,
    const float* __restrict__ W1, const float* __restrict__ W2,
    unsigned short* __restrict__ wt1, unsigned short* __restrict__ wt2) {
  __shared__ int red[256];
  int bkt = blockIdx.x >> 2;           // all 256 nodes of a block share a bucket
  int partial = 0;
  for (int j = threadIdx.x; j < bkt; j += 256) partial += part[j];
  red[threadIdx.x] = partial;
  __syncthreads();
  for (int off = 128; off; off >>= 1) {
    if (threadIdx.x < off) red[threadIdx.x] += red[threadIdx.x + off];
    __syncthreads();
  }
  int boff = red[0];
  int i = blockIdx.x * 256 + threadIdx.x;
  if (i >= NN) return;
  if (i < 32768) {             // fused weight split
    const float* W = (i < 16384) ? W1 : W2;
    unsigned short* wt = (i < 16384) ? wt1 : wt2;
    int ii = i & 16383;
    int k = ii >> 7, n = ii & 127;
    float w = W[ii];
    unsigned short h = f2bf(w);
    unsigned short l = f2bf(w - bf2f(h));
    wt[n * 128 + k] = h;
    wt[16384 + n * 128 + k] = l;
  }
  int r = rows[i] + boff;
  rows[i] = r;
  if (blockIdx.x == 390 && threadIdx.x == 0)
    rows[NN] = boff + part[NCB - 1];   // bkt==97 here: total padded edges
  int d = deg[i];
  int pd = (d + 7) & ~7;
  for (int k = r + d; k < r + pd; ++k) csr[k] = NN;  // dummy zero row
  int b = batch[i];
  int prev = (i == 0) ? -1 : batch[i - 1];
  for (int g = prev + 1; g <= b; ++g) start[g] = i;
  if (i == NN - 1)
    for (int g = b + 1; g <= NG; ++g) start[g] = NN;
}

// Per (bucket, cell-group): place srcs via LDS cursors at group-local bases.
__global__ __launch_bounds__(1024) void k_place2(const unsigned* __restrict__ stg,
                                                 const int* __restrict__ cnt,
                                                 const int* __restrict__ rows,
                                                 const int* __restrict__ deg8,
                                                 int* __restrict__ csr) {
  __shared__ int lrow[1024];
  __shared__ int lcur[1024];
  int b = blockIdx.x, g = blockIdx.y;
  int t = threadIdx.x;
  int w = t >> 6, lane = t & 63;
  int gid = (b << CSH) + t;
  int base = (gid < NN) ? rows[gid] : 0;
  for (int gp = 0; gp < g; ++gp) base += deg8[gp * DSL + gid];
  lrow[t] = base;
  lcur[t] = 0;
  __syncthreads();
  for (int blk = g * CPG + w; blk < (g + 1) * CPG; blk += 16) {
    int c = cnt[blk * NCB + b];
    const unsigned* p = stg + ((size_t)blk * NCB + b) * SCAP;
    for (int e = lane; e < c; e += 64) {
      unsigned x = p[e];
      int ld = x >> 17;
      int q = atomicAdd(&lcur[ld], 1);
      csr[lrow[ld] + q] = (int)(x & 0x1FFFFu);
    }
  }
}

// Layer-1: Hs(bf16) = diag(dinv) * (X_fp32 @ W), split-bf16 MFMA (3 terms).
// MERGED full-width, 512 threads: X read ONCE; W hi/lo in LDS (verified r12).
__global__ __launch_bounds__(512) void k_gemm_mfma(
    const float* __restrict__ X, const unsigned short* __restrict__ wth,
    const unsigned short* __restrict__ wtl, const float* __restrict__ dinv,
    unsigned short* __restrict__ Hs) {
  __shared__ __align__(16) unsigned short sWh[128 * 136];  // [n][k] pad 136
  __shared__ __align__(16) unsigned short sWl[128 * 136];
  __shared__ __align__(16) unsigned short sXh[128 * 40];   // [row][k-chunk 32]
  __shared__ __align__(16) unsigned short sXl[128 * 40];

  const int t = threadIdx.x;
  const int w = t >> 6, lane = t & 63;
  const int quad = lane >> 4, lr = lane & 15;
  const int wr = w & 3, wc = w >> 2;     // wave row-group 0..3, col-half 0..1
  const int row0 = blockIdx.x * 128;

  // zero the dummy row NN (read by k_aggregate pad slots)
  if (blockIdx.x == 0 && t < 64)
    *(unsigned*)&Hs[(size_t)NN * CH + t * 2] = 0u;

#pragma unroll
  for (int j = 0; j < 8; ++j) {
    int id = t + j * 512;
    int n = id >> 5, kk = (id & 31) * 4;
    *(ushort4*)&sWh[n * 136 + kk] = *(const ushort4*)&wth[n * 128 + kk];
    *(ushort4*)&sWl[n * 136 + kk] = *(const ushort4*)&wtl[n * 128 + kk];
  }

  float4v acc[2][4];
#pragma unroll
  for (int mi = 0; mi < 2; ++mi)
#pragma unroll
    for (int ni = 0; ni < 4; ++ni) acc[mi][ni] = (float4v){0.f, 0.f, 0.f, 0.f};

  for (int ks = 0; ks < 4; ++ks) {
    const int k0 = ks * 32;
    if (ks) __syncthreads();
#pragma unroll
    for (int i = 0; i < 2; ++i) {
      int row = i * 64 + (t >> 3);
      int seg = t & 7;
      int gr = row0 + row;
      float4 xv = {0.f, 0.f, 0.f, 0.f};
      if (gr < NN) xv = *(const float4*)&X[(size_t)gr * CH + k0 + seg * 4];
      ushort4 h, l;
      h.x = f2bf(xv.x); l.x = f2bf(xv.x - bf2f(h.x));
      h.y = f2bf(xv.y); l.y = f2bf(xv.y - bf2f(h.y));
      h.z = f2bf(xv.z); l.z = f2bf(xv.z - bf2f(h.z));
      h.w = f2bf(xv.w); l.w = f2bf(xv.w - bf2f(h.w));
      *(ushort4*)&sXh[row * 40 + seg * 4] = h;
      *(ushort4*)&sXl[row * 40 + seg * 4] = l;
    }
    __syncthreads();

    short8v ah[2], al[2];
#pragma unroll
    for (int mi = 0; mi < 2; ++mi) {
      int r = wr * 32 + mi * 16 + lr;
      ah[mi] = *(const short8v*)&sXh[r * 40 + quad * 8];
      al[mi] = *(const short8v*)&sXl[r * 40 + quad * 8];
    }
#pragma unroll
    for (int ni = 0; ni < 4; ++ni) {
      int n = wc * 64 + ni * 16 + lr;
      short8v bh = *(const short8v*)&sWh[n * 136 + k0 + quad * 8];
      short8v bl = *(const short8v*)&sWl[n * 136 + k0 + quad * 8];
#pragma unroll
      for (int mi = 0; mi < 2; ++mi) {
        acc[mi][ni] = __builtin_amdgcn_mfma_f32_16x16x32_bf16(ah[mi], bh, acc[mi][ni], 0, 0, 0);
        acc[mi][ni] = __builtin_amdgcn_mfma_f32_16x16x32_bf16(ah[mi], bl, acc[mi][ni], 0, 0, 0);
        acc[mi][ni] = __builtin_amdgcn_mfma_f32_16x16x32_bf16(al[mi], bh, acc[mi][ni], 0, 0, 0);
      }
    }
  }

#pragma unroll
  for (int mi = 0; mi < 2; ++mi) {
#pragma unroll
    for (int r = 0; r < 4; ++r) {
      int grow = row0 + wr * 32 + mi * 16 + quad * 4 + r;
      if (grow < NN) {
        float d = dinv[grow];
#pragma unroll
        for (int ni = 0; ni < 4; ++ni)
          Hs[(size_t)grow * CH + wc * 64 + ni * 16 + lr] = f2bf(d * acc[mi][ni][r]);
      }
    }
  }
}

// Layer-2: Hs(bf16) = diag(dinv) * (A_bf16 @ W). A exact bf16: 2 MFMA terms.
// MERGED full-width (verified r11): A read once, W in LDS, 2 blocks/CU.
__global__ __launch_bounds__(256) void k_gemm_bf(
    const unsigned short* __restrict__ A, const unsigned short* __restrict__ wth,
    const unsigned short* __restrict__ wtl, const float* __restrict__ dinv,
    unsigned short* __restrict__ Hs) {
  __shared__ __align__(16) unsigned short sWh[128 * 136];
  __shared__ __align__(16) unsigned short sWl[128 * 136];
  __shared__ __align__(16) unsigned short sA[128 * 40];

  const int t = threadIdx.x;
  const int w = t >> 6, lane = t & 63;
  const int quad = lane >> 4, lr = lane & 15;
  const int row0 = blockIdx.x * 128;

  if (blockIdx.x == 0 && t < 64)
    *(unsigned*)&Hs[(size_t)NN * CH + t * 2] = 0u;

#pragma unroll
  for (int j = 0; j < 16; ++j) {
    int id = t + j * 256;
    int n = id >> 5, kk = (id & 31) * 4;
    *(ushort4*)&sWh[n * 136 + kk] = *(const ushort4*)&wth[n * 128 + kk];
    *(ushort4*)&sWl[n * 136 + kk] = *(const ushort4*)&wtl[n * 128 + kk];
  }

  float4v acc[2][8];
#pragma unroll
  for (int mi = 0; mi < 2; ++mi)
#pragma unroll
    for (int ni = 0; ni < 8; ++ni) acc[mi][ni] = (float4v){0.f, 0.f, 0.f, 0.f};

  for (int ks = 0; ks < 4; ++ks) {
    const int k0 = ks * 32;
    if (ks) __syncthreads();
    // stage A[row0..row0+127][k0..k0+31] bf16: 8 KB, each thread 2x ushort4
#pragma unroll
    for (int i = 0; i < 2; ++i) {
      int id = t + i * 256;          // 512 ushort4 segments
      int row = id >> 2, seg = id & 3;
      int gr = row0 + row;
      ushort4 v = {0, 0, 0, 0};
      if (gr < NN) v = *(const ushort4*)&A[(size_t)gr * CH + k0 + seg * 8];
      *(ushort4*)&sA[row * 40 + seg * 8] = v;
      ushort4 v2 = {0, 0, 0, 0};
      if (gr < NN) v2 = *(const ushort4*)&A[(size_t)gr * CH + k0 + seg * 8 + 4];
      *(ushort4*)&sA[row * 40 + seg * 8 + 4] = v2;
    }
    __syncthreads();

    short8v ah[2];
#pragma unroll
    for (int mi = 0; mi < 2; ++mi) {
      int r = w * 32 + mi * 16 + lr;
      ah[mi] = *(const short8v*)&sA[r * 40 + quad * 8];
    }
#pragma unroll
    for (int ni = 0; ni < 8; ++ni) {
      int n = ni * 16 + lr;
      short8v bh = *(const short8v*)&sWh[n * 136 + k0 + quad * 8];
      short8v bl = *(const short8v*)&sWl[n * 136 + k0 + quad * 8];
#pragma unroll
      for (int mi = 0; mi < 2; ++mi) {
        acc[mi][ni] = __builtin_amdgcn_mfma_f32_16x16x32_bf16(ah[mi], bh, acc[mi][ni], 0, 0, 0);
        acc[mi][ni] = __builtin_amdgcn_mfma_f32_16x16x32_bf16(ah[mi], bl, acc[mi][ni], 0, 0, 0);
      }
    }
  }

#pragma unroll
  for (int mi = 0; mi < 2; ++mi) {
#pragma unroll
    for (int r = 0; r < 4; ++r) {
      int grow = row0 + w * 32 + mi * 16 + quad * 4 + r;
      if (grow < NN) {
        float d = dinv[grow];
#pragma unroll
        for (int ni = 0; ni < 8; ++ni)
          Hs[(size_t)grow * CH + ni * 16 + lr] = f2bf(d * acc[mi][ni][r]);
      }
    }
  }
}

// out(bf16)[i] = relu(dinv[i]*(Hs[i] + sum Hs[csr[e]]) + b). One wave per node.
// dwordx2 gathers: lanes 0-31 take even edges, 32-63 odd edges of each 8-group;
// each lane owns 4 channels; one shfl_xor(32) combines halves. (verified 60 us)
__global__ __launch_bounds__(256) void k_aggregate(
    const uint2* __restrict__ H2, const int* __restrict__ rows,
    const int* __restrict__ csr, const float* __restrict__ dinv,
    const float* __restrict__ bias, uint2* __restrict__ out) {
  int node = blockIdx.x * 4 + (threadIdx.x >> 6);
  if (node >= NN) return;
  int lane = threadIdx.x & 63;
  int h = lane >> 5, li = lane & 31;
  float a0 = 0.f, a1 = 0.f, a2 = 0.f, a3 = 0.f;
  int e0 = rows[node], e1 = rows[node + 1];  // padded, multiple of 8
  int nr = (e1 - e0) >> 3;                   // rounds of 8 edges
  if (nr) {
    const int* cp = csr + e0 + h;            // half h reads edges e0+h, e0+h+2, ...
    uint2 va[4], vb[4];

#define LOADQ(buf)                                                          \
  do {                                                                      \
    unsigned s0_ = (unsigned)cp[0], s1_ = (unsigned)cp[2];                  \
    unsigned s2_ = (unsigned)cp[4], s3_ = (unsigned)cp[6];                  \
    buf[0] = H2[(s0_ << 5) | li];                                           \
    buf[1] = H2[(s1_ << 5) | li];                                           \
    buf[2] = H2[(s2_ << 5) | li];                                           \
    buf[3] = H2[(s3_ << 5) | li];                                           \
    cp += 8;                                                                \
  } while (0)

#define ACCQ(buf)                                                           \
  do {                                                                      \
    _Pragma("unroll")                                                       \
    for (int k_ = 0; k_ < 4; ++k_) {                                        \
      a0 += bflo(buf[k_].x); a1 += bfhi(buf[k_].x);                         \
      a2 += bflo(buf[k_].y); a3 += bfhi(buf[k_].y);                         \
    }                                                                       \
  } while (0)

    LOADQ(va);
    int rem = nr - 1;
    while (rem >= 2) {
      LOADQ(vb); ACCQ(va);
      LOADQ(va); ACCQ(vb);
      rem -= 2;
    }
    if (rem) { LOADQ(vb); ACCQ(va); ACCQ(vb); }
    else     { ACCQ(va); }
#undef LOADQ
#undef ACCQ
  }
  // combine even-edge (h=0) and odd-edge (h=1) partial sums
  a0 += __shfl_xor(a0, 32);
  a1 += __shfl_xor(a1, 32);
  a2 += __shfl_xor(a2, 32);
  a3 += __shfl_xor(a3, 32);
  // self-loop term
  uint2 sv = H2[((unsigned)node << 5) | li];
  a0 += bflo(sv.x); a1 += bfhi(sv.x);
  a2 += bflo(sv.y); a3 += bfhi(sv.y);
  float d = dinv[node];
  float4 b4 = *(const float4*)&bias[li << 2];
  float o0 = fmaxf(fmaf(d, a0, b4.x), 0.f);
  float o1 = fmaxf(fmaf(d, a1, b4.y), 0.f);
  float o2 = fmaxf(fmaf(d, a2, b4.z), 0.f);
  float o3 = fmaxf(fmaf(d, a3, b4.w), 0.f);
  if (!h)
    out[((unsigned)node << 5) | li] = make_uint2(pack2(o0, o1), pack2(o2, o3));
}

// Fused per-graph pipeline: segmented mean pool -> MLP1 -> MLP2 -> out.
// Pooling vectorized: short8 (16 B) loads, 16 rows x 16 channel-octets/block.
__global__ __launch_bounds__(256) void k_head(
    const unsigned short* __restrict__ A, const int* __restrict__ start,
    const float* __restrict__ W3, const float* __restrict__ b3,
    const float* __restrict__ W4, const float* __restrict__ b4,
    float* __restrict__ out) {
  __shared__ float ppart[16][128];
  __shared__ float pooled[128];
  __shared__ float g1[128];
  int g = blockIdx.x;
  int t = threadIdx.x;
  int c8 = t & 15;            // channel octet 0..15
  int r = t >> 4;             // row slot 0..15
  int s0 = start[g], s1 = start[g + 1];
  float s[8] = {0.f, 0.f, 0.f, 0.f, 0.f, 0.f, 0.f, 0.f};
  for (int i = s0 + r; i < s1; i += 16) {
    short8v v = *(const short8v*)&A[(size_t)i * CH + c8 * 8];
#pragma unroll
    for (int j = 0; j < 8; ++j) s[j] += bf2f((unsigned short)v[j]);
  }
#pragma unroll
  for (int j = 0; j < 8; ++j) ppart[r][c8 * 8 + j] = s[j];
  __syncthreads();
  if (t < 128) {
    float n = fmaxf((float)(s1 - s0), 1.0f);
    float acc = 0.f;
#pragma unroll
    for (int rr = 0; rr < 16; ++rr) acc += ppart[rr][t];
    pooled[t] = acc / n;
  }
  __syncthreads();
  if (t < 128) {
    float acc = b3[t];
    for (int k = 0; k < 128; ++k) acc += pooled[k] * W3[k * CH + t];
    g1[t] = fmaxf(acc, 0.f);
  }
  __syncthreads();
  if (t < 64) {
    float acc = b4[t];
    for (int k = 0; k < 128; ++k) acc += g1[k] * W4[k * OC + t];
    out[(size_t)g * OC + t] = acc;
  }
}

extern "C" void kernel_launch(void* const* d_in, const int* in_sizes, int n_in,
                              void* d_out, int out_size, void* d_ws, size_t ws_size,
                              hipStream_t stream) {
  const float* X   = (const float*)d_in[0];
  const int* ei    = (const int*)d_in[1];
  const int* batch = (const int*)d_in[2];
  const float* W1  = (const float*)d_in[3];
  const float* b1  = (const float*)d_in[4];
  const float* W2  = (const float*)d_in[5];
  const float* b2  = (const float*)d_in[6];
  const float* W3  = (const float*)d_in[7];
  const float* b3  = (const float*)d_in[8];
  const float* W4  = (const float*)d_in[9];
  const float* b4  = (const float*)d_in[10];
  float* out = (float*)d_out;
  float* ws = (float*)d_ws;

  const int* src = ei;        // edge_index[0]
  const int* dst = ei + EE;   // edge_index[1]

  float* dinv = ws + O_DINV;
  int* rows   = (int*)(ws + O_ROWS);
  int* cnt    = (int*)(ws + O_CNT);
  int* part   = (int*)(ws + O_PART);
  int* start  = (int*)(ws + O_START);
  int* csr    = (int*)(ws + O_CSR);
  unsigned short* Hs = (unsigned short*)(ws + O_HS);
  unsigned* stg = (unsigned*)(ws + O_STG);
  unsigned short* wt1 = (unsigned short*)(ws + O_WT1);
  unsigned short* wt2 = (unsigned short*)(ws + O_WT2);
  unsigned short* A1 = (unsigned short*)(ws + O_A1);
  int* deg8   = (int*)(ws + O_DEG8);
  int* deg    = (int*)(ws + O_DEG);

  k_part<<<PBLK, 1024, 0, stream>>>(src, dst, cnt, stg);
  k_count2<<<dim3(NCB, NCG), 1024, 0, stream>>>(stg, cnt, deg8);
  k_scan1<<<NCB, 1024, 0, stream>>>(deg8, deg, rows, part, dinv);
  k_scan_add<<<(NN + 255) / 256, 256, 0, stream>>>(rows, part, deg, batch,
                                                   start, csr, W1, W2, wt1, wt2);
  k_place2<<<dim3(NCB, NCG), 1024, 0, stream>>>(stg, cnt, rows, deg8, csr);

  // layer 1 (fp32 X input, 3-term split MFMA, merged full-width: X read once)
  k_gemm_mfma<<<(NN + 127) / 128, 512, 0, stream>>>(X, wt1, wt1 + 16384, dinv, Hs);
  k_aggregate<<<(NN + 3) / 4, 256, 0, stream>>>((const uint2*)Hs, rows, csr, dinv, b1, (uint2*)A1);
  // layer 2 (bf16 A1 input, 2-term MFMA, merged full-width: A read once)
  k_gemm_bf<<<(NN + 127) / 128, 256, 0, stream>>>(A1, wt2, wt2 + 16384, dinv, Hs);
  k_aggregate<<<(NN + 3) / 4, 256, 0, stream>>>((const uint2*)Hs, rows, csr, dinv, b2, (uint2*)A1);

  k_head<<<NG, 256, 0, stream>>>(A1, start, W3, b3, W4, b4, out);
}